// Round 3
// baseline (3601.271 us; speedup 1.0000x reference)
//
#include <hip/hip_runtime.h>

#define HID 52
#define HID2 104
#define SCAN_CHUNK 1024   // 256 threads x 4 elems
#define EH_CHUNK 8192     // edges per block in hist/scatter (must match between the two)
#define NBUCK_MAX 1600    // LDS histogram capacity (N/64 <= 1600)

// ---------- edge bucketing: bucket = dst>>6, 8 slots per bucket (blockIdx&7) ----------

__global__ void ehist_kernel(const int* __restrict__ dst, int* __restrict__ counters,
                             int E, int nbuck) {
    __shared__ int lh[NBUCK_MAX];
    for (int i = threadIdx.x; i < nbuck; i += 256) lh[i] = 0;
    __syncthreads();
    int base = blockIdx.x * EH_CHUNK;
    int end = min(base + EH_CHUNK, E);
    for (int i = base + threadIdx.x; i < end; i += 256) atomicAdd(&lh[dst[i] >> 6], 1);
    __syncthreads();
    int slot = blockIdx.x & 7;
    for (int i = threadIdx.x; i < nbuck; i += 256) {
        int c = lh[i];
        if (c) atomicAdd(&counters[i * 8 + slot], c);
    }
}

__global__ void chunk_sum_kernel(const int* __restrict__ deg, int* __restrict__ bsum, int n) {
    __shared__ int sd[256];
    int base = blockIdx.x * SCAN_CHUNK;
    int s = 0;
    for (int i = threadIdx.x; i < SCAN_CHUNK; i += 256) {
        int g = base + i;
        s += (g < n) ? deg[g] : 0;
    }
    sd[threadIdx.x] = s;
    __syncthreads();
    for (int off = 128; off > 0; off >>= 1) {
        if (threadIdx.x < off) sd[threadIdx.x] += sd[threadIdx.x + off];
        __syncthreads();
    }
    if (threadIdx.x == 0) bsum[blockIdx.x] = sd[0];
}

// single block, 128 threads; nb <= 128. exclusive scan of bsum in place.
__global__ void scan_bsum_kernel(int* __restrict__ bsum, int nb,
                                 int* __restrict__ rowstart, int NSLOT, int E) {
    __shared__ int sd[128];
    int tid = threadIdx.x;
    int v = (tid < nb) ? bsum[tid] : 0;
    sd[tid] = v;
    __syncthreads();
    for (int off = 1; off < 128; off <<= 1) {
        int t = (tid >= off) ? sd[tid - off] : 0;
        __syncthreads();
        sd[tid] += t;
        __syncthreads();
    }
    if (tid < nb) bsum[tid] = sd[tid] - v;   // exclusive
    if (tid == 0) rowstart[NSLOT] = E;
}

__global__ void chunk_scan_kernel(const int* __restrict__ deg, const int* __restrict__ bsum_ex,
                                  int* __restrict__ rowstart, int* __restrict__ cursor, int n) {
    __shared__ int sd[256];
    int tid = threadIdx.x;
    int base = blockIdx.x * SCAN_CHUNK + tid * 4;
    int v0 = (base + 0 < n) ? deg[base + 0] : 0;
    int v1 = (base + 1 < n) ? deg[base + 1] : 0;
    int v2 = (base + 2 < n) ? deg[base + 2] : 0;
    int v3 = (base + 3 < n) ? deg[base + 3] : 0;
    int tsum = v0 + v1 + v2 + v3;
    sd[tid] = tsum;
    __syncthreads();
    for (int off = 1; off < 256; off <<= 1) {
        int t = (tid >= off) ? sd[tid - off] : 0;
        __syncthreads();
        sd[tid] += t;
        __syncthreads();
    }
    int ex = sd[tid] - tsum + bsum_ex[blockIdx.x];
    int p0 = ex, p1 = p0 + v0, p2 = p1 + v1, p3 = p2 + v2;
    if (base + 0 < n) { rowstart[base + 0] = p0; cursor[base + 0] = p0; }
    if (base + 1 < n) { rowstart[base + 1] = p1; cursor[base + 1] = p1; }
    if (base + 2 < n) { rowstart[base + 2] = p2; cursor[base + 2] = p2; }
    if (base + 3 < n) { rowstart[base + 3] = p3; cursor[base + 3] = p3; }
}

// packed edge word: (src << 6) | (dst & 63); grouped by (bucket, slot=blockIdx&7)
__global__ void escatter_kernel(const int* __restrict__ src, const int* __restrict__ dst,
                                int* __restrict__ cursor, unsigned int* __restrict__ packed,
                                int E) {
    int base = blockIdx.x * EH_CHUNK;
    int end = min(base + EH_CHUNK, E);
    int slot = blockIdx.x & 7;
    for (int i = base + threadIdx.x; i < end; i += 256) {
        int d = dst[i];
        int bucket = d >> 6;
        int pos = atomicAdd(&cursor[bucket * 8 + slot], 1);
        packed[pos] = ((unsigned int)src[i] << 6) | (unsigned int)(d & 63);
    }
}

// ---------- aggregation: one block per 64-node bucket, LDS fp32 tile ----------
// z[v] = (1+eps)*h[v] + sum_{e: dst=v} h[src[e]]
__global__ __launch_bounds__(256) void agg_kernel(const float* __restrict__ h,
                                                  const int* __restrict__ rowstart,
                                                  const unsigned int* __restrict__ packed,
                                                  const float* __restrict__ eps,
                                                  float* __restrict__ z, int n) {
    __shared__ float tile[64 * HID];   // 13312 B
    int bucket = blockIdx.x;
    for (int i = threadIdx.x; i < 64 * HID; i += 256) tile[i] = 0.f;
    __syncthreads();

    int beg = rowstart[bucket * 8];
    int end = rowstart[bucket * 8 + 8];   // 8 slots are contiguous in scan order
    int count = end - beg;
    int wave = threadIdx.x >> 6, lane = threadIdx.x & 63;
    int g = lane >> 4, sub = lane & 15;   // 4 edge-groups x 16 lanes; sub<13 active
    const float4* h4 = (const float4*)h;

    for (int wbase = wave * 64; wbase < count; wbase += 256) {
        int nb = min(64, count - wbase);
        unsigned int pk = (lane < nb) ? packed[beg + wbase + lane] : 0u;
#pragma unroll
        for (int j = 0; j < 16; j++) {
            int ei = (j << 2) | g;
            unsigned int p = __shfl(pk, ei);
            if (ei < nb && sub < 13) {
                int s = (int)(p >> 6);
                int off = (int)(p & 63u);
                float4 v = h4[(size_t)s * 13 + sub];
                float* t = &tile[off * HID + sub * 4];
                atomicAdd(&t[0], v.x);
                atomicAdd(&t[1], v.y);
                atomicAdd(&t[2], v.z);
                atomicAdd(&t[3], v.w);
            }
        }
    }
    __syncthreads();

    float scale = 1.0f + eps[0];
    int nodebase = bucket * 64;
    int total = min(64, n - nodebase) * HID;
    const float* hrow = h + (size_t)nodebase * HID;
    float* zrow = z + (size_t)nodebase * HID;
    for (int i = threadIdx.x; i < total; i += 256)
        zrow[i] = fmaf(scale, hrow[i], tile[i]);
}

// ---------- per-node 2-layer MLP ----------
__global__ void mlp_kernel(const float* __restrict__ z,
                           const float* __restrict__ w1, const float* __restrict__ b1,
                           const float* __restrict__ w2, const float* __restrict__ b2,
                           float* __restrict__ hout, int n) {
    __shared__ float s_w1[HID * HID2];
    __shared__ float s_w2[HID2 * HID];
    __shared__ float s_b1[HID2];
    __shared__ float s_b2[HID];
    int tid = threadIdx.x;
    for (int i = tid; i < HID * HID2; i += blockDim.x) s_w1[i] = w1[i];
    for (int i = tid; i < HID2 * HID; i += blockDim.x) s_w2[i] = w2[i];
    if (tid < HID2) s_b1[tid] = b1[tid];
    if (tid < HID)  s_b2[tid] = b2[tid];
    __syncthreads();

    int node = blockIdx.x * blockDim.x + tid;
    if (node >= n) return;

    float x[HID];
    const float4* zr = (const float4*)(z + (size_t)node * HID);
#pragma unroll
    for (int i = 0; i < HID / 4; i++) {
        float4 v = zr[i];
        x[4*i+0] = v.x; x[4*i+1] = v.y; x[4*i+2] = v.z; x[4*i+3] = v.w;
    }

    float4 acc[HID / 4];
#pragma unroll
    for (int k = 0; k < HID / 4; k++) acc[k] = ((const float4*)s_b2)[k];

    for (int j0 = 0; j0 < HID2; j0 += 4) {
        float4 s = *(const float4*)&s_b1[j0];
#pragma unroll
        for (int i = 0; i < HID; i++) {
            float4 w = *(const float4*)&s_w1[i * HID2 + j0];
            s.x = fmaf(x[i], w.x, s.x);
            s.y = fmaf(x[i], w.y, s.y);
            s.z = fmaf(x[i], w.z, s.z);
            s.w = fmaf(x[i], w.w, s.w);
        }
        s.x = fmaxf(s.x, 0.f); s.y = fmaxf(s.y, 0.f);
        s.z = fmaxf(s.z, 0.f); s.w = fmaxf(s.w, 0.f);
        const float4* r0 = (const float4*)&s_w2[(j0+0) * HID];
        const float4* r1 = (const float4*)&s_w2[(j0+1) * HID];
        const float4* r2 = (const float4*)&s_w2[(j0+2) * HID];
        const float4* r3 = (const float4*)&s_w2[(j0+3) * HID];
#pragma unroll
        for (int k = 0; k < HID / 4; k++) {
            float4 a = acc[k];
            float4 w0 = r0[k], w1v = r1[k], w2v = r2[k], w3v = r3[k];
            a.x = fmaf(s.x, w0.x, a.x); a.x = fmaf(s.y, w1v.x, a.x);
            a.x = fmaf(s.z, w2v.x, a.x); a.x = fmaf(s.w, w3v.x, a.x);
            a.y = fmaf(s.x, w0.y, a.y); a.y = fmaf(s.y, w1v.y, a.y);
            a.y = fmaf(s.z, w2v.y, a.y); a.y = fmaf(s.w, w3v.y, a.y);
            a.z = fmaf(s.x, w0.z, a.z); a.z = fmaf(s.y, w1v.z, a.z);
            a.z = fmaf(s.z, w2v.z, a.z); a.z = fmaf(s.w, w3v.z, a.z);
            a.w = fmaf(s.x, w0.w, a.w); a.w = fmaf(s.y, w1v.w, a.w);
            a.w = fmaf(s.z, w2v.w, a.w); a.w = fmaf(s.w, w3v.w, a.w);
            acc[k] = a;
        }
    }

    float4* orow = (float4*)(hout + (size_t)node * HID);
#pragma unroll
    for (int k = 0; k < HID / 4; k++) {
        float4 a = acc[k];
        a.x = fmaxf(a.x, 0.f); a.y = fmaxf(a.y, 0.f);
        a.z = fmaxf(a.z, 0.f); a.w = fmaxf(a.w, 0.f);
        orow[k] = a;
    }
}

// ---------- final linear ----------
__global__ void final_kernel(const float* __restrict__ h0, const float* __restrict__ h1,
                             const float* __restrict__ h2, const float* __restrict__ h3,
                             const float* __restrict__ lin_w, const float* __restrict__ lin_b,
                             float* __restrict__ out, int n) {
    __shared__ float s_lw[4 * HID * HID];
    __shared__ float s_lb[HID];
    int tid = threadIdx.x;
    for (int i = tid; i < 4 * HID * HID; i += blockDim.x) s_lw[i] = lin_w[i];
    if (tid < HID) s_lb[tid] = lin_b[tid];
    __syncthreads();

    int node = blockIdx.x * blockDim.x + tid;
    if (node >= n) return;

    float4 acc[HID / 4];
#pragma unroll
    for (int k = 0; k < HID / 4; k++) acc[k] = ((const float4*)s_lb)[k];

    const float* srcs[4] = {h0, h1, h2, h3};
#pragma unroll
    for (int b = 0; b < 4; b++) {
        const float4* xr = (const float4*)(srcs[b] + (size_t)node * HID);
#pragma unroll
        for (int i4 = 0; i4 < HID / 4; i4++) {
            float4 v = xr[i4];
            int ib = b * HID + 4 * i4;
            const float4* w0 = (const float4*)&s_lw[(ib+0) * HID];
            const float4* w1v = (const float4*)&s_lw[(ib+1) * HID];
            const float4* w2v = (const float4*)&s_lw[(ib+2) * HID];
            const float4* w3v = (const float4*)&s_lw[(ib+3) * HID];
#pragma unroll
            for (int k = 0; k < HID / 4; k++) {
                float4 a = acc[k];
                float4 a0 = w0[k], a1 = w1v[k], a2 = w2v[k], a3 = w3v[k];
                a.x = fmaf(v.x, a0.x, a.x); a.x = fmaf(v.y, a1.x, a.x);
                a.x = fmaf(v.z, a2.x, a.x); a.x = fmaf(v.w, a3.x, a.x);
                a.y = fmaf(v.x, a0.y, a.y); a.y = fmaf(v.y, a1.y, a.y);
                a.y = fmaf(v.z, a2.y, a.y); a.y = fmaf(v.w, a3.y, a.y);
                a.z = fmaf(v.x, a0.z, a.z); a.z = fmaf(v.y, a1.z, a.z);
                a.z = fmaf(v.z, a2.z, a.z); a.z = fmaf(v.w, a3.z, a.z);
                a.w = fmaf(v.x, a0.w, a.w); a.w = fmaf(v.y, a1.w, a.w);
                a.w = fmaf(v.z, a2.w, a.w); a.w = fmaf(v.w, a3.w, a.w);
                acc[k] = a;
            }
        }
    }

    float4* orow = (float4*)(out + (size_t)node * HID);
#pragma unroll
    for (int k = 0; k < HID / 4; k++) orow[k] = acc[k];
}

extern "C" void kernel_launch(void* const* d_in, const int* in_sizes, int n_in,
                              void* d_out, int out_size, void* d_ws, size_t ws_size,
                              hipStream_t stream) {
    const float* x     = (const float*)d_in[0];
    const int*   ei    = (const int*)d_in[1];
    const float* w1    = (const float*)d_in[2];
    const float* b1    = (const float*)d_in[3];
    const float* w2    = (const float*)d_in[4];
    const float* b2    = (const float*)d_in[5];
    const float* eps   = (const float*)d_in[6];
    const float* lin_w = (const float*)d_in[7];
    const float* lin_b = (const float*)d_in[8];
    float* out = (float*)d_out;

    const int N = in_sizes[0] / HID;       // 100000
    const int E = in_sizes[1] / 2;         // 3200000
    const int* src = ei;
    const int* dst = ei + E;

    const int NBUCK = (N + 63) / 64;       // 1563
    const int NSLOT = NBUCK * 8;           // 12504

    // workspace layout
    float* ws = (float*)d_ws;
    float* z  = ws;
    float* h1 = ws + (size_t)N * HID;
    float* h2 = h1 + (size_t)N * HID;
    float* h3 = h2 + (size_t)N * HID;
    float* houts[3] = {h1, h2, h3};
    int* ibase     = (int*)(h3 + (size_t)N * HID);
    int* counters  = ibase;                    // NSLOT
    int* rowstart  = counters + NSLOT;         // NSLOT+1
    int* cursor    = rowstart + NSLOT + 1;     // NSLOT
    int* bsum      = cursor + NSLOT;           // <=128
    unsigned int* packed = (unsigned int*)(bsum + 128);  // E

    const int BLK = 256;
    const int NEB = (E + EH_CHUNK - 1) / EH_CHUNK;        // 391
    const int NB = (NSLOT + SCAN_CHUNK - 1) / SCAN_CHUNK; // 13
    dim3 blk(BLK);
    dim3 grid_node((N + BLK - 1) / BLK);

    // ---- bucket-CSR build (once per call) ----
    hipMemsetAsync(counters, 0, (size_t)NSLOT * sizeof(int), stream);
    ehist_kernel<<<NEB, blk, 0, stream>>>(dst, counters, E, NBUCK);
    chunk_sum_kernel<<<NB, blk, 0, stream>>>(counters, bsum, NSLOT);
    scan_bsum_kernel<<<1, 128, 0, stream>>>(bsum, NB, rowstart, NSLOT, E);
    chunk_scan_kernel<<<NB, blk, 0, stream>>>(counters, bsum, rowstart, cursor, NSLOT);
    escatter_kernel<<<NEB, blk, 0, stream>>>(src, dst, cursor, packed, E);

    // ---- layers ----
    const float* hprev = x;
    for (int l = 0; l < 3; l++) {
        agg_kernel<<<NBUCK, blk, 0, stream>>>(hprev, rowstart, packed, eps + l, z, N);
        mlp_kernel<<<grid_node, blk, 0, stream>>>(z,
                                                  w1 + (size_t)l * HID * HID2,
                                                  b1 + (size_t)l * HID2,
                                                  w2 + (size_t)l * HID2 * HID,
                                                  b2 + (size_t)l * HID,
                                                  houts[l], N);
        hprev = houts[l];
    }
    final_kernel<<<grid_node, blk, 0, stream>>>(x, h1, h2, h3, lin_w, lin_b, out, N);
}

// Round 4
// 1188.622 us; speedup vs baseline: 3.0298x; 3.0298x over previous
//
#include <hip/hip_runtime.h>

#define HID 52
#define HID2 104
#define SCAN_CHUNK 1024   // 256 threads x 4 elems
#define EH_CHUNK 8192     // edges per block in hist/scatter (must match between the two)
#define NBUCK_MAX 1600    // LDS histogram capacity (N/64 <= 1600)

// ---------- edge bucketing: bucket = dst>>6, 8 slots per bucket (blockIdx&7) ----------

__global__ void ehist_kernel(const int* __restrict__ dst, int* __restrict__ counters,
                             int E, int nbuck) {
    __shared__ int lh[NBUCK_MAX];
    for (int i = threadIdx.x; i < nbuck; i += 256) lh[i] = 0;
    __syncthreads();
    int base = blockIdx.x * EH_CHUNK;
    int end = min(base + EH_CHUNK, E);
    for (int i = base + threadIdx.x; i < end; i += 256) atomicAdd(&lh[dst[i] >> 6], 1);
    __syncthreads();
    int slot = blockIdx.x & 7;
    for (int i = threadIdx.x; i < nbuck; i += 256) {
        int c = lh[i];
        if (c) atomicAdd(&counters[i * 8 + slot], c);
    }
}

__global__ void chunk_sum_kernel(const int* __restrict__ deg, int* __restrict__ bsum, int n) {
    __shared__ int sd[256];
    int base = blockIdx.x * SCAN_CHUNK;
    int s = 0;
    for (int i = threadIdx.x; i < SCAN_CHUNK; i += 256) {
        int g = base + i;
        s += (g < n) ? deg[g] : 0;
    }
    sd[threadIdx.x] = s;
    __syncthreads();
    for (int off = 128; off > 0; off >>= 1) {
        if (threadIdx.x < off) sd[threadIdx.x] += sd[threadIdx.x + off];
        __syncthreads();
    }
    if (threadIdx.x == 0) bsum[blockIdx.x] = sd[0];
}

// single block, 128 threads; nb <= 128. exclusive scan of bsum in place.
__global__ void scan_bsum_kernel(int* __restrict__ bsum, int nb,
                                 int* __restrict__ rowstart, int NSLOT, int E) {
    __shared__ int sd[128];
    int tid = threadIdx.x;
    int v = (tid < nb) ? bsum[tid] : 0;
    sd[tid] = v;
    __syncthreads();
    for (int off = 1; off < 128; off <<= 1) {
        int t = (tid >= off) ? sd[tid - off] : 0;
        __syncthreads();
        sd[tid] += t;
        __syncthreads();
    }
    if (tid < nb) bsum[tid] = sd[tid] - v;   // exclusive
    if (tid == 0) rowstart[NSLOT] = E;
}

__global__ void chunk_scan_kernel(const int* __restrict__ deg, const int* __restrict__ bsum_ex,
                                  int* __restrict__ rowstart, int* __restrict__ cursor, int n) {
    __shared__ int sd[256];
    int tid = threadIdx.x;
    int base = blockIdx.x * SCAN_CHUNK + tid * 4;
    int v0 = (base + 0 < n) ? deg[base + 0] : 0;
    int v1 = (base + 1 < n) ? deg[base + 1] : 0;
    int v2 = (base + 2 < n) ? deg[base + 2] : 0;
    int v3 = (base + 3 < n) ? deg[base + 3] : 0;
    int tsum = v0 + v1 + v2 + v3;
    sd[tid] = tsum;
    __syncthreads();
    for (int off = 1; off < 256; off <<= 1) {
        int t = (tid >= off) ? sd[tid - off] : 0;
        __syncthreads();
        sd[tid] += t;
        __syncthreads();
    }
    int ex = sd[tid] - tsum + bsum_ex[blockIdx.x];
    int p0 = ex, p1 = p0 + v0, p2 = p1 + v1, p3 = p2 + v2;
    if (base + 0 < n) { rowstart[base + 0] = p0; cursor[base + 0] = p0; }
    if (base + 1 < n) { rowstart[base + 1] = p1; cursor[base + 1] = p1; }
    if (base + 2 < n) { rowstart[base + 2] = p2; cursor[base + 2] = p2; }
    if (base + 3 < n) { rowstart[base + 3] = p3; cursor[base + 3] = p3; }
}

// packed edge word: (src << 6) | (dst & 63); grouped by (bucket, slot=blockIdx&7)
__global__ void escatter_kernel(const int* __restrict__ src, const int* __restrict__ dst,
                                int* __restrict__ cursor, unsigned int* __restrict__ packed,
                                int E) {
    int base = blockIdx.x * EH_CHUNK;
    int end = min(base + EH_CHUNK, E);
    int slot = blockIdx.x & 7;
    for (int i = base + threadIdx.x; i < end; i += 256) {
        int d = dst[i];
        int bucket = d >> 6;
        int pos = atomicAdd(&cursor[bucket * 8 + slot], 1);
        packed[pos] = ((unsigned int)src[i] << 6) | (unsigned int)(d & 63);
    }
}

// per-bucket counting sort: packed (bucket-grouped) -> srcsorted (node-grouped),
// and emit node-level rowstart. One block per bucket.
__global__ __launch_bounds__(256) void bucket_sort_kernel(const unsigned int* __restrict__ packed,
                                                          const int* __restrict__ slot_rowstart,
                                                          int* __restrict__ srcsorted,
                                                          int* __restrict__ node_rowstart,
                                                          int N) {
    __shared__ int cnt[64];
    __shared__ int curs[64];
    int bucket = blockIdx.x;
    int beg = slot_rowstart[bucket * 8];
    int end = slot_rowstart[bucket * 8 + 8];
    if (threadIdx.x < 64) cnt[threadIdx.x] = 0;
    __syncthreads();
    for (int i = beg + threadIdx.x; i < end; i += 256)
        atomicAdd(&cnt[packed[i] & 63u], 1);
    __syncthreads();
    if (threadIdx.x < 64) {          // wave 0: 64-lane inclusive scan
        int lane = threadIdx.x;
        int v = cnt[lane];
        int inc = v;
        for (int off = 1; off < 64; off <<= 1) {
            int t = __shfl_up(inc, off);
            if (lane >= off) inc += t;
        }
        int ex = beg + inc - v;      // exclusive prefix
        curs[lane] = ex;
        int node = bucket * 64 + lane;
        if (node <= N) node_rowstart[node] = ex;
    }
    __syncthreads();
    for (int i = beg + threadIdx.x; i < end; i += 256) {
        unsigned int p = packed[i];
        int pos = atomicAdd(&curs[p & 63u], 1);
        srcsorted[pos] = (int)(p >> 6);
    }
}

// ---------- aggregation: one wave per node, register accumulation, float4 gathers ----------
// z[v] = (1+eps)*h[v] + sum_{e: dst=v} h[src[e]]
__global__ __launch_bounds__(256) void agg_kernel(const float* __restrict__ h,
                                                  const int* __restrict__ nrs,
                                                  const int* __restrict__ srcsorted,
                                                  const float* __restrict__ eps,
                                                  float* __restrict__ z, int n) {
    int wid = (blockIdx.x * blockDim.x + threadIdx.x) >> 6;
    if (wid >= n) return;
    int lane = threadIdx.x & 63;
    int g = lane >> 4, sub = lane & 15;     // 4 edge-groups x 16 lanes; sub<13 active
    int beg = nrs[wid];
    int end = nrs[wid + 1];
    const float4* h4 = (const float4*)h;

    float4 acc = make_float4(0.f, 0.f, 0.f, 0.f);
    for (int b = beg; b < end; b += 64) {
        int cnt = min(64, end - b);
        int idx = (lane < cnt) ? srcsorted[b + lane] : 0;
        int jmax = (cnt + 3) >> 2;
        for (int j = 0; j < jmax; j++) {
            int ei = (j << 2) | g;
            int s = __shfl(idx, ei);
            if (ei < cnt && sub < 13) {
                float4 v = h4[(size_t)s * 13 + sub];
                acc.x += v.x; acc.y += v.y; acc.z += v.z; acc.w += v.w;
            }
        }
    }
    // reduce the 4 groups (lane^16, lane^32)
#pragma unroll
    for (int m = 16; m <= 32; m <<= 1) {
        acc.x += __shfl_xor(acc.x, m);
        acc.y += __shfl_xor(acc.y, m);
        acc.z += __shfl_xor(acc.z, m);
        acc.w += __shfl_xor(acc.w, m);
    }
    if (lane < 13) {
        float scale = 1.0f + eps[0];
        float4 hv = h4[(size_t)wid * 13 + lane];
        float4 o;
        o.x = fmaf(scale, hv.x, acc.x);
        o.y = fmaf(scale, hv.y, acc.y);
        o.z = fmaf(scale, hv.z, acc.z);
        o.w = fmaf(scale, hv.w, acc.w);
        ((float4*)z)[(size_t)wid * 13 + lane] = o;
    }
}

// ---------- per-node 2-layer MLP ----------
__global__ void mlp_kernel(const float* __restrict__ z,
                           const float* __restrict__ w1, const float* __restrict__ b1,
                           const float* __restrict__ w2, const float* __restrict__ b2,
                           float* __restrict__ hout, int n) {
    __shared__ float s_w1[HID * HID2];
    __shared__ float s_w2[HID2 * HID];
    __shared__ float s_b1[HID2];
    __shared__ float s_b2[HID];
    int tid = threadIdx.x;
    for (int i = tid; i < HID * HID2; i += blockDim.x) s_w1[i] = w1[i];
    for (int i = tid; i < HID2 * HID; i += blockDim.x) s_w2[i] = w2[i];
    if (tid < HID2) s_b1[tid] = b1[tid];
    if (tid < HID)  s_b2[tid] = b2[tid];
    __syncthreads();

    int node = blockIdx.x * blockDim.x + tid;
    if (node >= n) return;

    float x[HID];
    const float4* zr = (const float4*)(z + (size_t)node * HID);
#pragma unroll
    for (int i = 0; i < HID / 4; i++) {
        float4 v = zr[i];
        x[4*i+0] = v.x; x[4*i+1] = v.y; x[4*i+2] = v.z; x[4*i+3] = v.w;
    }

    float4 acc[HID / 4];
#pragma unroll
    for (int k = 0; k < HID / 4; k++) acc[k] = ((const float4*)s_b2)[k];

    for (int j0 = 0; j0 < HID2; j0 += 4) {
        float4 s = *(const float4*)&s_b1[j0];
#pragma unroll
        for (int i = 0; i < HID; i++) {
            float4 w = *(const float4*)&s_w1[i * HID2 + j0];
            s.x = fmaf(x[i], w.x, s.x);
            s.y = fmaf(x[i], w.y, s.y);
            s.z = fmaf(x[i], w.z, s.z);
            s.w = fmaf(x[i], w.w, s.w);
        }
        s.x = fmaxf(s.x, 0.f); s.y = fmaxf(s.y, 0.f);
        s.z = fmaxf(s.z, 0.f); s.w = fmaxf(s.w, 0.f);
        const float4* r0 = (const float4*)&s_w2[(j0+0) * HID];
        const float4* r1 = (const float4*)&s_w2[(j0+1) * HID];
        const float4* r2 = (const float4*)&s_w2[(j0+2) * HID];
        const float4* r3 = (const float4*)&s_w2[(j0+3) * HID];
#pragma unroll
        for (int k = 0; k < HID / 4; k++) {
            float4 a = acc[k];
            float4 w0 = r0[k], w1v = r1[k], w2v = r2[k], w3v = r3[k];
            a.x = fmaf(s.x, w0.x, a.x); a.x = fmaf(s.y, w1v.x, a.x);
            a.x = fmaf(s.z, w2v.x, a.x); a.x = fmaf(s.w, w3v.x, a.x);
            a.y = fmaf(s.x, w0.y, a.y); a.y = fmaf(s.y, w1v.y, a.y);
            a.y = fmaf(s.z, w2v.y, a.y); a.y = fmaf(s.w, w3v.y, a.y);
            a.z = fmaf(s.x, w0.z, a.z); a.z = fmaf(s.y, w1v.z, a.z);
            a.z = fmaf(s.z, w2v.z, a.z); a.z = fmaf(s.w, w3v.z, a.z);
            a.w = fmaf(s.x, w0.w, a.w); a.w = fmaf(s.y, w1v.w, a.w);
            a.w = fmaf(s.z, w2v.w, a.w); a.w = fmaf(s.w, w3v.w, a.w);
            acc[k] = a;
        }
    }

    float4* orow = (float4*)(hout + (size_t)node * HID);
#pragma unroll
    for (int k = 0; k < HID / 4; k++) {
        float4 a = acc[k];
        a.x = fmaxf(a.x, 0.f); a.y = fmaxf(a.y, 0.f);
        a.z = fmaxf(a.z, 0.f); a.w = fmaxf(a.w, 0.f);
        orow[k] = a;
    }
}

// ---------- final linear ----------
__global__ void final_kernel(const float* __restrict__ h0, const float* __restrict__ h1,
                             const float* __restrict__ h2, const float* __restrict__ h3,
                             const float* __restrict__ lin_w, const float* __restrict__ lin_b,
                             float* __restrict__ out, int n) {
    __shared__ float s_lw[4 * HID * HID];
    __shared__ float s_lb[HID];
    int tid = threadIdx.x;
    for (int i = tid; i < 4 * HID * HID; i += blockDim.x) s_lw[i] = lin_w[i];
    if (tid < HID) s_lb[tid] = lin_b[tid];
    __syncthreads();

    int node = blockIdx.x * blockDim.x + tid;
    if (node >= n) return;

    float4 acc[HID / 4];
#pragma unroll
    for (int k = 0; k < HID / 4; k++) acc[k] = ((const float4*)s_lb)[k];

    const float* srcs[4] = {h0, h1, h2, h3};
#pragma unroll
    for (int b = 0; b < 4; b++) {
        const float4* xr = (const float4*)(srcs[b] + (size_t)node * HID);
#pragma unroll
        for (int i4 = 0; i4 < HID / 4; i4++) {
            float4 v = xr[i4];
            int ib = b * HID + 4 * i4;
            const float4* w0 = (const float4*)&s_lw[(ib+0) * HID];
            const float4* w1v = (const float4*)&s_lw[(ib+1) * HID];
            const float4* w2v = (const float4*)&s_lw[(ib+2) * HID];
            const float4* w3v = (const float4*)&s_lw[(ib+3) * HID];
#pragma unroll
            for (int k = 0; k < HID / 4; k++) {
                float4 a = acc[k];
                float4 a0 = w0[k], a1 = w1v[k], a2 = w2v[k], a3 = w3v[k];
                a.x = fmaf(v.x, a0.x, a.x); a.x = fmaf(v.y, a1.x, a.x);
                a.x = fmaf(v.z, a2.x, a.x); a.x = fmaf(v.w, a3.x, a.x);
                a.y = fmaf(v.x, a0.y, a.y); a.y = fmaf(v.y, a1.y, a.y);
                a.y = fmaf(v.z, a2.y, a.y); a.y = fmaf(v.w, a3.y, a.y);
                a.z = fmaf(v.x, a0.z, a.z); a.z = fmaf(v.y, a1.z, a.z);
                a.z = fmaf(v.z, a2.z, a.z); a.z = fmaf(v.w, a3.z, a.z);
                a.w = fmaf(v.x, a0.w, a.w); a.w = fmaf(v.y, a1.w, a.w);
                a.w = fmaf(v.z, a2.w, a.w); a.w = fmaf(v.w, a3.w, a.w);
                acc[k] = a;
            }
        }
    }

    float4* orow = (float4*)(out + (size_t)node * HID);
#pragma unroll
    for (int k = 0; k < HID / 4; k++) orow[k] = acc[k];
}

extern "C" void kernel_launch(void* const* d_in, const int* in_sizes, int n_in,
                              void* d_out, int out_size, void* d_ws, size_t ws_size,
                              hipStream_t stream) {
    const float* x     = (const float*)d_in[0];
    const int*   ei    = (const int*)d_in[1];
    const float* w1    = (const float*)d_in[2];
    const float* b1    = (const float*)d_in[3];
    const float* w2    = (const float*)d_in[4];
    const float* b2    = (const float*)d_in[5];
    const float* eps   = (const float*)d_in[6];
    const float* lin_w = (const float*)d_in[7];
    const float* lin_b = (const float*)d_in[8];
    float* out = (float*)d_out;

    const int N = in_sizes[0] / HID;       // 100000
    const int E = in_sizes[1] / 2;         // 3200000
    const int* src = ei;
    const int* dst = ei + E;

    const int NBUCK = (N + 63) / 64;       // 1563
    const int NSLOT = NBUCK * 8;           // 12504

    // workspace layout
    float* ws = (float*)d_ws;
    float* z  = ws;
    float* h1 = ws + (size_t)N * HID;
    float* h2 = h1 + (size_t)N * HID;
    float* h3 = h2 + (size_t)N * HID;
    float* houts[3] = {h1, h2, h3};
    int* ibase     = (int*)(h3 + (size_t)N * HID);
    int* counters  = ibase;                    // NSLOT
    int* rowstart  = counters + NSLOT;         // NSLOT+1
    int* cursor    = rowstart + NSLOT + 1;     // NSLOT
    int* bsum      = cursor + NSLOT;           // <=128
    int* nrs       = bsum + 128;               // N+1 node rowstart
    unsigned int* packed = (unsigned int*)(nrs + N + 1);  // E
    int* srcsorted = (int*)(packed + E);       // E

    const int BLK = 256;
    const int NEB = (E + EH_CHUNK - 1) / EH_CHUNK;        // 391
    const int NB = (NSLOT + SCAN_CHUNK - 1) / SCAN_CHUNK; // 13
    dim3 blk(BLK);
    dim3 grid_node((N + BLK - 1) / BLK);
    dim3 grid_agg(((size_t)N * 64 + BLK - 1) / BLK);

    // ---- bucket-CSR build + per-bucket counting sort (once per call) ----
    hipMemsetAsync(counters, 0, (size_t)NSLOT * sizeof(int), stream);
    ehist_kernel<<<NEB, blk, 0, stream>>>(dst, counters, E, NBUCK);
    chunk_sum_kernel<<<NB, blk, 0, stream>>>(counters, bsum, NSLOT);
    scan_bsum_kernel<<<1, 128, 0, stream>>>(bsum, NB, rowstart, NSLOT, E);
    chunk_scan_kernel<<<NB, blk, 0, stream>>>(counters, bsum, rowstart, cursor, NSLOT);
    escatter_kernel<<<NEB, blk, 0, stream>>>(src, dst, cursor, packed, E);
    bucket_sort_kernel<<<NBUCK, blk, 0, stream>>>(packed, rowstart, srcsorted, nrs, N);

    // ---- layers ----
    const float* hprev = x;
    for (int l = 0; l < 3; l++) {
        agg_kernel<<<grid_agg, blk, 0, stream>>>(hprev, nrs, srcsorted, eps + l, z, N);
        mlp_kernel<<<grid_node, blk, 0, stream>>>(z,
                                                  w1 + (size_t)l * HID * HID2,
                                                  b1 + (size_t)l * HID2,
                                                  w2 + (size_t)l * HID2 * HID,
                                                  b2 + (size_t)l * HID,
                                                  houts[l], N);
        hprev = houts[l];
    }
    final_kernel<<<grid_node, blk, 0, stream>>>(x, h1, h2, h3, lin_w, lin_b, out, N);
}

// Round 5
// 547.529 us; speedup vs baseline: 6.5773x; 2.1709x over previous
//
#include <hip/hip_runtime.h>

#define HID 52
#define HID2 104
#define SCAN_CHUNK 1024
#define EH_CHUNK 8192
#define NBUCK_MAX 1600

typedef unsigned short ushort_t;
typedef unsigned int uint_t;
typedef short bf16x8 __attribute__((ext_vector_type(8)));
typedef float f32x4 __attribute__((ext_vector_type(4)));

__device__ __forceinline__ ushort_t f2bf(float f) {
    union { float f; uint_t u; } c; c.f = f;
    uint_t u = c.u + 0x7FFFu + ((c.u >> 16) & 1u);   // RNE
    return (ushort_t)(u >> 16);
}
__device__ __forceinline__ float bflo(uint_t u) {   // low bf16 of packed pair
    union { uint_t u; float f; } c; c.u = u << 16; return c.f;
}
__device__ __forceinline__ float bfhi(uint_t u) {   // high bf16
    union { uint_t u; float f; } c; c.u = u & 0xFFFF0000u; return c.f;
}

// ---------- edge bucketing (unchanged R4 pipeline) ----------

__global__ void ehist_kernel(const int* __restrict__ dst, int* __restrict__ counters,
                             int E, int nbuck) {
    __shared__ int lh[NBUCK_MAX];
    for (int i = threadIdx.x; i < nbuck; i += 256) lh[i] = 0;
    __syncthreads();
    int base = blockIdx.x * EH_CHUNK;
    int end = min(base + EH_CHUNK, E);
    for (int i = base + threadIdx.x; i < end; i += 256) atomicAdd(&lh[dst[i] >> 6], 1);
    __syncthreads();
    int slot = blockIdx.x & 7;
    for (int i = threadIdx.x; i < nbuck; i += 256) {
        int c = lh[i];
        if (c) atomicAdd(&counters[i * 8 + slot], c);
    }
}

__global__ void chunk_sum_kernel(const int* __restrict__ deg, int* __restrict__ bsum, int n) {
    __shared__ int sd[256];
    int base = blockIdx.x * SCAN_CHUNK;
    int s = 0;
    for (int i = threadIdx.x; i < SCAN_CHUNK; i += 256) {
        int g = base + i;
        s += (g < n) ? deg[g] : 0;
    }
    sd[threadIdx.x] = s;
    __syncthreads();
    for (int off = 128; off > 0; off >>= 1) {
        if (threadIdx.x < off) sd[threadIdx.x] += sd[threadIdx.x + off];
        __syncthreads();
    }
    if (threadIdx.x == 0) bsum[blockIdx.x] = sd[0];
}

__global__ void scan_bsum_kernel(int* __restrict__ bsum, int nb,
                                 int* __restrict__ rowstart, int NSLOT, int E) {
    __shared__ int sd[128];
    int tid = threadIdx.x;
    int v = (tid < nb) ? bsum[tid] : 0;
    sd[tid] = v;
    __syncthreads();
    for (int off = 1; off < 128; off <<= 1) {
        int t = (tid >= off) ? sd[tid - off] : 0;
        __syncthreads();
        sd[tid] += t;
        __syncthreads();
    }
    if (tid < nb) bsum[tid] = sd[tid] - v;
    if (tid == 0) rowstart[NSLOT] = E;
}

__global__ void chunk_scan_kernel(const int* __restrict__ deg, const int* __restrict__ bsum_ex,
                                  int* __restrict__ rowstart, int* __restrict__ cursor, int n) {
    __shared__ int sd[256];
    int tid = threadIdx.x;
    int base = blockIdx.x * SCAN_CHUNK + tid * 4;
    int v0 = (base + 0 < n) ? deg[base + 0] : 0;
    int v1 = (base + 1 < n) ? deg[base + 1] : 0;
    int v2 = (base + 2 < n) ? deg[base + 2] : 0;
    int v3 = (base + 3 < n) ? deg[base + 3] : 0;
    int tsum = v0 + v1 + v2 + v3;
    sd[tid] = tsum;
    __syncthreads();
    for (int off = 1; off < 256; off <<= 1) {
        int t = (tid >= off) ? sd[tid - off] : 0;
        __syncthreads();
        sd[tid] += t;
        __syncthreads();
    }
    int ex = sd[tid] - tsum + bsum_ex[blockIdx.x];
    int p0 = ex, p1 = p0 + v0, p2 = p1 + v1, p3 = p2 + v2;
    if (base + 0 < n) { rowstart[base + 0] = p0; cursor[base + 0] = p0; }
    if (base + 1 < n) { rowstart[base + 1] = p1; cursor[base + 1] = p1; }
    if (base + 2 < n) { rowstart[base + 2] = p2; cursor[base + 2] = p2; }
    if (base + 3 < n) { rowstart[base + 3] = p3; cursor[base + 3] = p3; }
}

__global__ void escatter_kernel(const int* __restrict__ src, const int* __restrict__ dst,
                                int* __restrict__ cursor, unsigned int* __restrict__ packed,
                                int E) {
    int base = blockIdx.x * EH_CHUNK;
    int end = min(base + EH_CHUNK, E);
    int slot = blockIdx.x & 7;
    for (int i = base + threadIdx.x; i < end; i += 256) {
        int d = dst[i];
        int bucket = d >> 6;
        int pos = atomicAdd(&cursor[bucket * 8 + slot], 1);
        packed[pos] = ((unsigned int)src[i] << 6) | (unsigned int)(d & 63);
    }
}

__global__ __launch_bounds__(256) void bucket_sort_kernel(const unsigned int* __restrict__ packed,
                                                          const int* __restrict__ slot_rowstart,
                                                          int* __restrict__ srcsorted,
                                                          int* __restrict__ node_rowstart,
                                                          int N) {
    __shared__ int cnt[64];
    __shared__ int curs[64];
    int bucket = blockIdx.x;
    int beg = slot_rowstart[bucket * 8];
    int end = slot_rowstart[bucket * 8 + 8];
    if (threadIdx.x < 64) cnt[threadIdx.x] = 0;
    __syncthreads();
    for (int i = beg + threadIdx.x; i < end; i += 256)
        atomicAdd(&cnt[packed[i] & 63u], 1);
    __syncthreads();
    if (threadIdx.x < 64) {
        int lane = threadIdx.x;
        int v = cnt[lane];
        int inc = v;
        for (int off = 1; off < 64; off <<= 1) {
            int t = __shfl_up(inc, off);
            if (lane >= off) inc += t;
        }
        int ex = beg + inc - v;
        curs[lane] = ex;
        int node = bucket * 64 + lane;
        if (node <= N) node_rowstart[node] = ex;
    }
    __syncthreads();
    for (int i = beg + threadIdx.x; i < end; i += 256) {
        unsigned int p = packed[i];
        int pos = atomicAdd(&curs[p & 63u], 1);
        srcsorted[pos] = (int)(p >> 6);
    }
}

// ---------- converters ----------

// x fp32 [N][52] -> bf16 [N][64] zero-padded
__global__ void conv_x_kernel(const float* __restrict__ x, ushort_t* __restrict__ xb, int n) {
    int t = blockIdx.x * 256 + threadIdx.x;
    if (t >= n * 16) return;
    int node = t >> 4, p = t & 15;
    int c0 = p * 4;
    ushort_t o[4];
#pragma unroll
    for (int j = 0; j < 4; j++) {
        int c = c0 + j;
        o[j] = (c < HID) ? f2bf(x[(size_t)node * HID + c]) : 0;
    }
    uint_t u0 = (uint_t)o[0] | ((uint_t)o[1] << 16);
    uint_t u1 = (uint_t)o[2] | ((uint_t)o[3] << 16);
    *(uint2*)(xb + (size_t)node * 64 + c0) = make_uint2(u0, u1);
}

// weights -> fragment-linear bf16 (B-operand layout: n=lane&15, k=quad*8+j)
// w1f: [3][7ct][2ks][64][8]   w2f: [3][4ct][4ks][64][8]   linf: [4ct][8ks][64][8]
__global__ void conv_w_kernel(const float* __restrict__ w1, const float* __restrict__ w2,
                              const float* __restrict__ lin_w,
                              ushort_t* __restrict__ w1f, ushort_t* __restrict__ w2f,
                              ushort_t* __restrict__ linf) {
    int t = blockIdx.x * 256 + threadIdx.x;
    int gid = t >> 6, lane = t & 63;
    if (gid >= 122) return;
    int m = lane & 15, q = lane >> 4;
    ushort_t o[8];
    ushort_t* dstp;
    if (gid < 42) {                       // w1: K=52->64, N=104->112
        int l = gid / 14, r = gid % 14, ct = r >> 1, ks = r & 1;
        int nn = ct * 16 + m;
#pragma unroll
        for (int j = 0; j < 8; j++) {
            int k = ks * 32 + q * 8 + j;
            o[j] = (k < HID && nn < HID2) ? f2bf(w1[((size_t)l * HID + k) * HID2 + nn]) : 0;
        }
        dstp = w1f + ((size_t)(l * 14 + ct * 2 + ks) * 64 + lane) * 8;
    } else if (gid < 90) {                // w2: K=104->128, N=52->64
        int g2 = gid - 42, l = g2 / 16, r = g2 % 16, ct = r >> 2, ks = r & 3;
        int nn = ct * 16 + m;
#pragma unroll
        for (int j = 0; j < 8; j++) {
            int k = ks * 32 + q * 8 + j;
            o[j] = (k < HID2 && nn < HID) ? f2bf(w2[((size_t)l * HID2 + k) * HID + nn]) : 0;
        }
        dstp = w2f + ((size_t)(l * 16 + ct * 4 + ks) * 64 + lane) * 8;
    } else {                              // lin_w: K=4 segs of 52->64 (256), N=52->64
        int g2 = gid - 90, ct = g2 >> 3, ks = g2 & 7;
        int nn = ct * 16 + m;
#pragma unroll
        for (int j = 0; j < 8; j++) {
            int kg = ks * 32 + q * 8 + j;
            int seg = kg >> 6, kk = kg & 63;
            o[j] = (kk < HID && nn < HID) ? f2bf(lin_w[((size_t)seg * HID + kk) * HID + nn]) : 0;
        }
        dstp = linf + ((size_t)(ct * 8 + ks) * 64 + lane) * 8;
    }
    uint4 u;
    u.x = (uint_t)o[0] | ((uint_t)o[1] << 16);
    u.y = (uint_t)o[2] | ((uint_t)o[3] << 16);
    u.z = (uint_t)o[4] | ((uint_t)o[5] << 16);
    u.w = (uint_t)o[6] | ((uint_t)o[7] << 16);
    *(uint4*)dstp = u;
}

// ---------- aggregation: wave per node, bf16 gather, fp32 regs ----------
// zb[v] = bf16( (1+eps)*hb[v] + sum hb[src] ), [N][64] layout
__global__ __launch_bounds__(256) void agg_kernel(const ushort_t* __restrict__ hb,
                                                  const int* __restrict__ nrs,
                                                  const int* __restrict__ srcsorted,
                                                  const float* __restrict__ eps,
                                                  ushort_t* __restrict__ zb, int n) {
    int wid = (blockIdx.x * blockDim.x + threadIdx.x) >> 6;
    if (wid >= n) return;
    int lane = threadIdx.x & 63;
    int g = lane >> 3, sub = lane & 7;    // 8 edge-groups x 8 lanes; lane owns cols sub*8..+7
    int beg = nrs[wid], end = nrs[wid + 1];
    float a0=0,a1=0,a2=0,a3=0,a4=0,a5=0,a6=0,a7=0;
    for (int b = beg; b < end; b += 64) {
        int cnt = min(64, end - b);
        int idx = (lane < cnt) ? srcsorted[b + lane] : 0;
        int jmax = (cnt + 7) >> 3;
        for (int j = 0; j < jmax; j++) {
            int ei = (j << 3) | g;
            int s = __shfl(idx, ei);
            if (ei < cnt) {
                uint4 v = *(const uint4*)(hb + (size_t)s * 64 + sub * 8);
                a0 += bflo(v.x); a1 += bfhi(v.x);
                a2 += bflo(v.y); a3 += bfhi(v.y);
                a4 += bflo(v.z); a5 += bfhi(v.z);
                a6 += bflo(v.w); a7 += bfhi(v.w);
            }
        }
    }
#pragma unroll
    for (int msk = 8; msk <= 32; msk <<= 1) {
        a0 += __shfl_xor(a0, msk); a1 += __shfl_xor(a1, msk);
        a2 += __shfl_xor(a2, msk); a3 += __shfl_xor(a3, msk);
        a4 += __shfl_xor(a4, msk); a5 += __shfl_xor(a5, msk);
        a6 += __shfl_xor(a6, msk); a7 += __shfl_xor(a7, msk);
    }
    if (lane < 8) {
        float sc = 1.0f + eps[0];
        uint4 sv = *(const uint4*)(hb + (size_t)wid * 64 + lane * 8);
        float o0 = fmaf(sc, bflo(sv.x), a0), o1 = fmaf(sc, bfhi(sv.x), a1);
        float o2 = fmaf(sc, bflo(sv.y), a2), o3 = fmaf(sc, bfhi(sv.y), a3);
        float o4 = fmaf(sc, bflo(sv.z), a4), o5 = fmaf(sc, bfhi(sv.z), a5);
        float o6 = fmaf(sc, bflo(sv.w), a6), o7 = fmaf(sc, bfhi(sv.w), a7);
        uint4 u;
        u.x = (uint_t)f2bf(o0) | ((uint_t)f2bf(o1) << 16);
        u.y = (uint_t)f2bf(o2) | ((uint_t)f2bf(o3) << 16);
        u.z = (uint_t)f2bf(o4) | ((uint_t)f2bf(o5) << 16);
        u.w = (uint_t)f2bf(o6) | ((uint_t)f2bf(o7) << 16);
        *(uint4*)(zb + (size_t)wid * 64 + lane * 8) = u;
    }
}

// ---------- MFMA fused 2-layer MLP: block = 64 nodes, wave = 16 nodes ----------
#define HSTRIDE 136
__global__ __launch_bounds__(256) void mlp_kernel(const ushort_t* __restrict__ zb,
                                                  const ushort_t* __restrict__ w1f,
                                                  const float* __restrict__ b1,
                                                  const ushort_t* __restrict__ w2f,
                                                  const float* __restrict__ b2,
                                                  ushort_t* __restrict__ hbout, int n) {
    __shared__ ushort_t hid[64 * HSTRIDE];
    int tid = threadIdx.x;
    int w = tid >> 6, lane = tid & 63, m = lane & 15, q = lane >> 4;
    // zero k-pad cols 104..135
    for (int i = tid; i < 64 * 32; i += 256) {
        int r = i >> 5, c = HID2 + (i & 31);
        hid[r * HSTRIDE + c] = 0;
    }
    __syncthreads();

    int nb = blockIdx.x * 64 + w * 16;
    // ---- GEMM1: [16 x 52] @ [52 x 104] ----
    f32x4 acc1[7];
#pragma unroll
    for (int ct = 0; ct < 7; ct++) {
        int col = ct * 16 + m;
        float bv = (col < HID2) ? b1[col] : 0.f;
        acc1[ct] = (f32x4){bv, bv, bv, bv};
    }
    int anode = min(nb + m, n - 1);
#pragma unroll
    for (int ks = 0; ks < 2; ks++) {
        bf16x8 a = *(const bf16x8*)(zb + (size_t)anode * 64 + ks * 32 + q * 8);
#pragma unroll
        for (int ct = 0; ct < 7; ct++) {
            bf16x8 b = *(const bf16x8*)(w1f + ((size_t)(ct * 2 + ks) * 64 + lane) * 8);
            acc1[ct] = __builtin_amdgcn_mfma_f32_16x16x32_bf16(a, b, acc1[ct], 0, 0, 0);
        }
    }
    // relu -> LDS bf16 (wave-private rows, no barrier needed before own reads)
#pragma unroll
    for (int ct = 0; ct < 7; ct++) {
#pragma unroll
        for (int r = 0; r < 4; r++) {
            float v = fmaxf(acc1[ct][r], 0.f);
            int row = w * 16 + q * 4 + r;
            hid[row * HSTRIDE + ct * 16 + m] = f2bf(v);
        }
    }
    // ---- GEMM2: [16 x 104] @ [104 x 52] ----
    f32x4 acc2[4];
#pragma unroll
    for (int ct = 0; ct < 4; ct++) {
        int col = ct * 16 + m;
        float bv = (col < HID) ? b2[col] : 0.f;
        acc2[ct] = (f32x4){bv, bv, bv, bv};
    }
#pragma unroll
    for (int ks = 0; ks < 4; ks++) {
        bf16x8 a = *(const bf16x8*)&hid[(w * 16 + m) * HSTRIDE + ks * 32 + q * 8];
#pragma unroll
        for (int ct = 0; ct < 4; ct++) {
            bf16x8 b = *(const bf16x8*)(w2f + ((size_t)(ct * 4 + ks) * 64 + lane) * 8);
            acc2[ct] = __builtin_amdgcn_mfma_f32_16x16x32_bf16(a, b, acc2[ct], 0, 0, 0);
        }
    }
    // outer relu -> hbout bf16 [N][64] (pad cols produce 0 naturally)
#pragma unroll
    for (int ct = 0; ct < 4; ct++) {
#pragma unroll
        for (int r = 0; r < 4; r++) {
            int node = nb + q * 4 + r;
            if (node < n) {
                float v = fmaxf(acc2[ct][r], 0.f);
                hbout[(size_t)node * 64 + ct * 16 + m] = f2bf(v);
            }
        }
    }
}

// ---------- MFMA final: concat(4 segs) [N x 256pad] @ [256 x 52] ----------
__global__ __launch_bounds__(256) void final_kernel(const ushort_t* __restrict__ xb,
                                                    const ushort_t* __restrict__ h1b,
                                                    const ushort_t* __restrict__ h2b,
                                                    const ushort_t* __restrict__ h3b,
                                                    const ushort_t* __restrict__ linf,
                                                    const float* __restrict__ lin_b,
                                                    float* __restrict__ out, int ntiles) {
    int tid = threadIdx.x;
    int w = tid >> 6, lane = tid & 63, m = lane & 15, q = lane >> 4;
    int tile = blockIdx.x * 4 + w;
    if (tile >= ntiles) return;
    int nb = tile * 16;
    const ushort_t* segs[4] = {xb, h1b, h2b, h3b};
    f32x4 acc[4];
#pragma unroll
    for (int ct = 0; ct < 4; ct++) {
        int col = ct * 16 + m;
        float bv = (col < HID) ? lin_b[col] : 0.f;
        acc[ct] = (f32x4){bv, bv, bv, bv};
    }
#pragma unroll
    for (int ks = 0; ks < 8; ks++) {
        const ushort_t* p = segs[ks >> 1];
        bf16x8 a = *(const bf16x8*)(p + (size_t)(nb + m) * 64 + (ks & 1) * 32 + q * 8);
#pragma unroll
        for (int ct = 0; ct < 4; ct++) {
            bf16x8 b = *(const bf16x8*)(linf + ((size_t)(ct * 8 + ks) * 64 + lane) * 8);
            acc[ct] = __builtin_amdgcn_mfma_f32_16x16x32_bf16(a, b, acc[ct], 0, 0, 0);
        }
    }
#pragma unroll
    for (int ct = 0; ct < 4; ct++) {
        int col = ct * 16 + m;
        if (col < HID) {
#pragma unroll
            for (int r = 0; r < 4; r++)
                out[(size_t)(nb + q * 4 + r) * HID + col] = acc[ct][r];
        }
    }
}

extern "C" void kernel_launch(void* const* d_in, const int* in_sizes, int n_in,
                              void* d_out, int out_size, void* d_ws, size_t ws_size,
                              hipStream_t stream) {
    const float* x     = (const float*)d_in[0];
    const int*   ei    = (const int*)d_in[1];
    const float* w1    = (const float*)d_in[2];
    const float* b1    = (const float*)d_in[3];
    const float* w2    = (const float*)d_in[4];
    const float* b2    = (const float*)d_in[5];
    const float* eps   = (const float*)d_in[6];
    const float* lin_w = (const float*)d_in[7];
    const float* lin_b = (const float*)d_in[8];
    float* out = (float*)d_out;

    const int N = in_sizes[0] / HID;       // 100000
    const int E = in_sizes[1] / 2;         // 3200000
    const int* src = ei;
    const int* dst = ei + E;

    const int NBUCK = (N + 63) / 64;       // 1563
    const int NSLOT = NBUCK * 8;           // 12504

    // ---- workspace layout (16B-aligned blocks) ----
    char* p = (char*)d_ws;
    ushort_t* xb  = (ushort_t*)p;  p += (size_t)N * 64 * 2;   // 12.8 MB
    ushort_t* zb  = (ushort_t*)p;  p += (size_t)N * 64 * 2;
    ushort_t* h1b = (ushort_t*)p;  p += (size_t)N * 64 * 2;
    ushort_t* h2b = (ushort_t*)p;  p += (size_t)N * 64 * 2;
    ushort_t* h3b = (ushort_t*)p;  p += (size_t)N * 64 * 2;
    ushort_t* w1f = (ushort_t*)p;  p += 3 * 14 * 512 * 2;
    ushort_t* w2f = (ushort_t*)p;  p += 3 * 16 * 512 * 2;
    ushort_t* linf= (ushort_t*)p;  p += 32 * 512 * 2;
    int* counters  = (int*)p;      p += (size_t)NSLOT * 4;
    int* rowstart  = (int*)p;      p += (size_t)(NSLOT + 1) * 4;
    int* cursor    = (int*)p;      p += (size_t)NSLOT * 4;
    int* bsum      = (int*)p;      p += 128 * 4;
    int* nrs       = (int*)p;      p += (size_t)(N + 4) * 4;
    unsigned int* packed = (unsigned int*)p;  p += (size_t)E * 4;
    int* srcsorted = (int*)p;

    ushort_t* hbs[4] = {xb, h1b, h2b, h3b};

    const int BLK = 256;
    const int NEB = (E + EH_CHUNK - 1) / EH_CHUNK;
    const int NB = (NSLOT + SCAN_CHUNK - 1) / SCAN_CHUNK;
    dim3 blk(BLK);
    dim3 grid_agg(((size_t)N * 64 + BLK - 1) / BLK);

    // ---- CSR build + converters ----
    hipMemsetAsync(counters, 0, (size_t)NSLOT * sizeof(int), stream);
    ehist_kernel<<<NEB, blk, 0, stream>>>(dst, counters, E, NBUCK);
    chunk_sum_kernel<<<NB, blk, 0, stream>>>(counters, bsum, NSLOT);
    scan_bsum_kernel<<<1, 128, 0, stream>>>(bsum, NB, rowstart, NSLOT, E);
    chunk_scan_kernel<<<NB, blk, 0, stream>>>(counters, bsum, rowstart, cursor, NSLOT);
    escatter_kernel<<<NEB, blk, 0, stream>>>(src, dst, cursor, packed, E);
    bucket_sort_kernel<<<NBUCK, blk, 0, stream>>>(packed, rowstart, srcsorted, nrs, N);
    conv_x_kernel<<<(N * 16 + BLK - 1) / BLK, blk, 0, stream>>>(x, xb, N);
    conv_w_kernel<<<(122 * 64 + BLK - 1) / BLK, blk, 0, stream>>>(w1, w2, lin_w, w1f, w2f, linf);

    // ---- layers ----
    for (int l = 0; l < 3; l++) {
        agg_kernel<<<grid_agg, blk, 0, stream>>>(hbs[l], nrs, srcsorted, eps + l, zb, N);
        mlp_kernel<<<NBUCK, blk, 0, stream>>>(zb,
                                              w1f + (size_t)l * 14 * 512,
                                              b1 + (size_t)l * HID2,
                                              w2f + (size_t)l * 16 * 512,
                                              b2 + (size_t)l * HID,
                                              hbs[l + 1], N);
    }
    final_kernel<<<(6250 + 3) / 4 + 1, blk, 0, stream>>>(xb, h1b, h2b, h3b, linf, lin_b,
                                                         out, (N + 15) / 16);
}

// Round 6
// 417.852 us; speedup vs baseline: 8.6185x; 1.3103x over previous
//
#include <hip/hip_runtime.h>

#define HID 52
#define HID2 104
#define P1_CHUNK 8192
#define NBIN_MAX 512      // bins of 256 nodes; N <= 131072

typedef unsigned short ushort_t;
typedef unsigned int uint_t;
typedef short bf16x8 __attribute__((ext_vector_type(8)));
typedef float f32x4 __attribute__((ext_vector_type(4)));

__device__ __forceinline__ ushort_t f2bf(float f) {
    union { float f; uint_t u; } c; c.f = f;
    uint_t u = c.u + 0x7FFFu + ((c.u >> 16) & 1u);   // RNE
    return (ushort_t)(u >> 16);
}
__device__ __forceinline__ float bflo(uint_t u) {
    union { uint_t u; float f; } c; c.u = u << 16; return c.f;
}
__device__ __forceinline__ float bfhi(uint_t u) {
    union { uint_t u; float f; } c; c.u = u & 0xFFFF0000u; return c.f;
}

// ---------- two-pass dst-radix CSR build ----------

// global bin histogram (bin = dst>>8)
__global__ __launch_bounds__(256) void bhist_kernel(const int* __restrict__ dst,
                                                    int* __restrict__ ghist, int E) {
    __shared__ int lh[NBIN_MAX];
    int tid = threadIdx.x;
    lh[tid] = 0; lh[tid + 256] = 0;
    __syncthreads();
    int base = blockIdx.x * P1_CHUNK;
    int cend = min(P1_CHUNK, E - base);
    for (int i = tid; i < cend; i += 256) atomicAdd(&lh[dst[base + i] >> 8], 1);
    __syncthreads();
    int c = lh[tid];       if (c) atomicAdd(&ghist[tid], c);
    c = lh[tid + 256];     if (c) atomicAdd(&ghist[tid + 256], c);
}

// single block: exclusive scan of ghist -> binstart, gcur; nrs[N]=E
__global__ __launch_bounds__(256) void bscan_kernel(const int* __restrict__ ghist,
                                                    int* __restrict__ binstart,
                                                    int* __restrict__ gcur,
                                                    int* __restrict__ nrs,
                                                    int NBIN, int N, int E) {
    __shared__ int c[NBIN_MAX];
    __shared__ int ps[256];
    int tid = threadIdx.x;
    int b0 = 2 * tid, b1 = 2 * tid + 1;
    c[b0] = ghist[b0]; c[b1] = ghist[b1];
    __syncthreads();
    int pair = c[b0] + c[b1];
    ps[tid] = pair;
    __syncthreads();
    for (int off = 1; off < 256; off <<= 1) {
        int t = (tid >= off) ? ps[tid - off] : 0;
        __syncthreads();
        ps[tid] += t;
        __syncthreads();
    }
    int ex = ps[tid] - pair;
    binstart[b0] = ex;        gcur[b0] = ex;
    binstart[b1] = ex + c[b0]; gcur[b1] = ex + c[b0];
    if (tid == 0) { binstart[NBIN] = E; nrs[N] = E; }
}

// pass 1: bin-partition edges with LDS staging; coalesced run writes
__global__ __launch_bounds__(256) void pass1_kernel(const int* __restrict__ src,
                                                    const int* __restrict__ dst,
                                                    int* __restrict__ gcur,
                                                    uint_t* __restrict__ packed, int E) {
    __shared__ uint_t stage[P1_CHUNK];      // 32 KB
    __shared__ ushort_t sbin[P1_CHUNK];     // 16 KB
    __shared__ int cnt[NBIN_MAX];           // 2 KB
    __shared__ int sst[NBIN_MAX];           // 2 KB
    __shared__ int curs[NBIN_MAX];          // 2 KB
    __shared__ int gbase[NBIN_MAX];         // 2 KB
    __shared__ int ps[256];                 // 1 KB
    int tid = threadIdx.x;
    int base = blockIdx.x * P1_CHUNK;
    int cend = min(P1_CHUNK, E - base);
    cnt[tid] = 0; cnt[tid + 256] = 0;
    __syncthreads();
    for (int i = tid; i < cend; i += 256) atomicAdd(&cnt[dst[base + i] >> 8], 1);
    __syncthreads();
    int b0 = 2 * tid, b1 = 2 * tid + 1;
    int c0 = cnt[b0], c1 = cnt[b1];
    int pair = c0 + c1;
    ps[tid] = pair;
    __syncthreads();
    for (int off = 1; off < 256; off <<= 1) {
        int t = (tid >= off) ? ps[tid - off] : 0;
        __syncthreads();
        ps[tid] += t;
        __syncthreads();
    }
    int ex = ps[tid] - pair;
    sst[b0] = ex;       curs[b0] = ex;
    sst[b1] = ex + c0;  curs[b1] = ex + c0;
    gbase[b0] = c0 ? atomicAdd(&gcur[b0], c0) : 0;
    gbase[b1] = c1 ? atomicAdd(&gcur[b1], c1) : 0;
    __syncthreads();
    for (int i = tid; i < cend; i += 256) {
        int d = dst[base + i];
        int s = src[base + i];
        int b = d >> 8;
        int pos = atomicAdd(&curs[b], 1);
        stage[pos] = ((uint_t)s << 8) | (uint_t)(d & 255);
        sbin[pos] = (ushort_t)b;
    }
    __syncthreads();
    for (int i = tid; i < cend; i += 256) {
        int b = sbin[i];
        packed[gbase[b] + (i - sst[b])] = stage[i];
    }
}

// pass 2: per-bin counting sort over 256 local nodes -> srcsorted + nrs
__global__ __launch_bounds__(256) void pass2_kernel(const uint_t* __restrict__ packed,
                                                    const int* __restrict__ binstart,
                                                    int* __restrict__ srcsorted,
                                                    int* __restrict__ nrs, int N) {
    __shared__ int ncnt[256];
    __shared__ int ps[256];
    __shared__ int curs[256];
    int b = blockIdx.x;
    int beg = binstart[b], end = binstart[b + 1];
    int tid = threadIdx.x;
    ncnt[tid] = 0;
    __syncthreads();
    for (int i = beg + tid; i < end; i += 256) atomicAdd(&ncnt[packed[i] & 255u], 1);
    __syncthreads();
    int v = ncnt[tid];
    ps[tid] = v;
    __syncthreads();
    for (int off = 1; off < 256; off <<= 1) {
        int t = (tid >= off) ? ps[tid - off] : 0;
        __syncthreads();
        ps[tid] += t;
        __syncthreads();
    }
    int ex = ps[tid] - v;
    int node = b * 256 + tid;
    if (node < N) nrs[node] = beg + ex;
    curs[tid] = beg + ex;
    __syncthreads();
    for (int i = beg + tid; i < end; i += 256) {
        uint_t p = packed[i];
        int pos = atomicAdd(&curs[p & 255u], 1);
        srcsorted[pos] = (int)(p >> 8);
    }
}

// ---------- converters ----------

__global__ void conv_x_kernel(const float* __restrict__ x, ushort_t* __restrict__ xb, int n) {
    int t = blockIdx.x * 256 + threadIdx.x;
    if (t >= n * 16) return;
    int node = t >> 4, p = t & 15;
    int c0 = p * 4;
    ushort_t o[4];
#pragma unroll
    for (int j = 0; j < 4; j++) {
        int c = c0 + j;
        o[j] = (c < HID) ? f2bf(x[(size_t)node * HID + c]) : 0;
    }
    uint_t u0 = (uint_t)o[0] | ((uint_t)o[1] << 16);
    uint_t u1 = (uint_t)o[2] | ((uint_t)o[3] << 16);
    *(uint2*)(xb + (size_t)node * 64 + c0) = make_uint2(u0, u1);
}

__global__ void conv_w_kernel(const float* __restrict__ w1, const float* __restrict__ w2,
                              const float* __restrict__ lin_w,
                              ushort_t* __restrict__ w1f, ushort_t* __restrict__ w2f,
                              ushort_t* __restrict__ linf) {
    int t = blockIdx.x * 256 + threadIdx.x;
    int gid = t >> 6, lane = t & 63;
    if (gid >= 122) return;
    int m = lane & 15, q = lane >> 4;
    ushort_t o[8];
    ushort_t* dstp;
    if (gid < 42) {
        int l = gid / 14, r = gid % 14, ct = r >> 1, ks = r & 1;
        int nn = ct * 16 + m;
#pragma unroll
        for (int j = 0; j < 8; j++) {
            int k = ks * 32 + q * 8 + j;
            o[j] = (k < HID && nn < HID2) ? f2bf(w1[((size_t)l * HID + k) * HID2 + nn]) : 0;
        }
        dstp = w1f + ((size_t)(l * 14 + ct * 2 + ks) * 64 + lane) * 8;
    } else if (gid < 90) {
        int g2 = gid - 42, l = g2 / 16, r = g2 % 16, ct = r >> 2, ks = r & 3;
        int nn = ct * 16 + m;
#pragma unroll
        for (int j = 0; j < 8; j++) {
            int k = ks * 32 + q * 8 + j;
            o[j] = (k < HID2 && nn < HID) ? f2bf(w2[((size_t)l * HID2 + k) * HID + nn]) : 0;
        }
        dstp = w2f + ((size_t)(l * 16 + ct * 4 + ks) * 64 + lane) * 8;
    } else {
        int g2 = gid - 90, ct = g2 >> 3, ks = g2 & 7;
        int nn = ct * 16 + m;
#pragma unroll
        for (int j = 0; j < 8; j++) {
            int kg = ks * 32 + q * 8 + j;
            int seg = kg >> 6, kk = kg & 63;
            o[j] = (kk < HID && nn < HID) ? f2bf(lin_w[((size_t)seg * HID + kk) * HID + nn]) : 0;
        }
        dstp = linf + ((size_t)(ct * 8 + ks) * 64 + lane) * 8;
    }
    uint4 u;
    u.x = (uint_t)o[0] | ((uint_t)o[1] << 16);
    u.y = (uint_t)o[2] | ((uint_t)o[3] << 16);
    u.z = (uint_t)o[4] | ((uint_t)o[5] << 16);
    u.w = (uint_t)o[6] | ((uint_t)o[7] << 16);
    *(uint4*)dstp = u;
}

// ---------- aggregation: wave per node, bf16 gather, fp32 regs ----------
__global__ __launch_bounds__(256) void agg_kernel(const ushort_t* __restrict__ hb,
                                                  const int* __restrict__ nrs,
                                                  const int* __restrict__ srcsorted,
                                                  const float* __restrict__ eps,
                                                  ushort_t* __restrict__ zb, int n) {
    int wid = (blockIdx.x * blockDim.x + threadIdx.x) >> 6;
    if (wid >= n) return;
    int lane = threadIdx.x & 63;
    int g = lane >> 3, sub = lane & 7;
    int beg = nrs[wid], end = nrs[wid + 1];
    float a0=0,a1=0,a2=0,a3=0,a4=0,a5=0,a6=0,a7=0;
    for (int b = beg; b < end; b += 64) {
        int cnt = min(64, end - b);
        int idx = (lane < cnt) ? srcsorted[b + lane] : 0;
        int jmax = (cnt + 7) >> 3;
        for (int j = 0; j < jmax; j++) {
            int ei = (j << 3) | g;
            int s = __shfl(idx, ei);
            if (ei < cnt) {
                uint4 v = *(const uint4*)(hb + (size_t)s * 64 + sub * 8);
                a0 += bflo(v.x); a1 += bfhi(v.x);
                a2 += bflo(v.y); a3 += bfhi(v.y);
                a4 += bflo(v.z); a5 += bfhi(v.z);
                a6 += bflo(v.w); a7 += bfhi(v.w);
            }
        }
    }
#pragma unroll
    for (int msk = 8; msk <= 32; msk <<= 1) {
        a0 += __shfl_xor(a0, msk); a1 += __shfl_xor(a1, msk);
        a2 += __shfl_xor(a2, msk); a3 += __shfl_xor(a3, msk);
        a4 += __shfl_xor(a4, msk); a5 += __shfl_xor(a5, msk);
        a6 += __shfl_xor(a6, msk); a7 += __shfl_xor(a7, msk);
    }
    if (lane < 8) {
        float sc = 1.0f + eps[0];
        uint4 sv = *(const uint4*)(hb + (size_t)wid * 64 + lane * 8);
        float o0 = fmaf(sc, bflo(sv.x), a0), o1 = fmaf(sc, bfhi(sv.x), a1);
        float o2 = fmaf(sc, bflo(sv.y), a2), o3 = fmaf(sc, bfhi(sv.y), a3);
        float o4 = fmaf(sc, bflo(sv.z), a4), o5 = fmaf(sc, bfhi(sv.z), a5);
        float o6 = fmaf(sc, bflo(sv.w), a6), o7 = fmaf(sc, bfhi(sv.w), a7);
        uint4 u;
        u.x = (uint_t)f2bf(o0) | ((uint_t)f2bf(o1) << 16);
        u.y = (uint_t)f2bf(o2) | ((uint_t)f2bf(o3) << 16);
        u.z = (uint_t)f2bf(o4) | ((uint_t)f2bf(o5) << 16);
        u.w = (uint_t)f2bf(o6) | ((uint_t)f2bf(o7) << 16);
        *(uint4*)(zb + (size_t)wid * 64 + lane * 8) = u;
    }
}

// ---------- MFMA fused 2-layer MLP ----------
#define HSTRIDE 136
__global__ __launch_bounds__(256) void mlp_kernel(const ushort_t* __restrict__ zb,
                                                  const ushort_t* __restrict__ w1f,
                                                  const float* __restrict__ b1,
                                                  const ushort_t* __restrict__ w2f,
                                                  const float* __restrict__ b2,
                                                  ushort_t* __restrict__ hbout, int n) {
    __shared__ ushort_t hid[64 * HSTRIDE];
    int tid = threadIdx.x;
    int w = tid >> 6, lane = tid & 63, m = lane & 15, q = lane >> 4;
    for (int i = tid; i < 64 * 32; i += 256) {
        int r = i >> 5, c = HID2 + (i & 31);
        hid[r * HSTRIDE + c] = 0;
    }
    __syncthreads();

    int nb = blockIdx.x * 64 + w * 16;
    f32x4 acc1[7];
#pragma unroll
    for (int ct = 0; ct < 7; ct++) {
        int col = ct * 16 + m;
        float bv = (col < HID2) ? b1[col] : 0.f;
        acc1[ct] = (f32x4){bv, bv, bv, bv};
    }
    int anode = min(nb + m, n - 1);
#pragma unroll
    for (int ks = 0; ks < 2; ks++) {
        bf16x8 a = *(const bf16x8*)(zb + (size_t)anode * 64 + ks * 32 + q * 8);
#pragma unroll
        for (int ct = 0; ct < 7; ct++) {
            bf16x8 b = *(const bf16x8*)(w1f + ((size_t)(ct * 2 + ks) * 64 + lane) * 8);
            acc1[ct] = __builtin_amdgcn_mfma_f32_16x16x32_bf16(a, b, acc1[ct], 0, 0, 0);
        }
    }
#pragma unroll
    for (int ct = 0; ct < 7; ct++) {
#pragma unroll
        for (int r = 0; r < 4; r++) {
            float v = fmaxf(acc1[ct][r], 0.f);
            int row = w * 16 + q * 4 + r;
            hid[row * HSTRIDE + ct * 16 + m] = f2bf(v);
        }
    }
    f32x4 acc2[4];
#pragma unroll
    for (int ct = 0; ct < 4; ct++) {
        int col = ct * 16 + m;
        float bv = (col < HID) ? b2[col] : 0.f;
        acc2[ct] = (f32x4){bv, bv, bv, bv};
    }
#pragma unroll
    for (int ks = 0; ks < 4; ks++) {
        bf16x8 a = *(const bf16x8*)&hid[(w * 16 + m) * HSTRIDE + ks * 32 + q * 8];
#pragma unroll
        for (int ct = 0; ct < 4; ct++) {
            bf16x8 b = *(const bf16x8*)(w2f + ((size_t)(ct * 4 + ks) * 64 + lane) * 8);
            acc2[ct] = __builtin_amdgcn_mfma_f32_16x16x32_bf16(a, b, acc2[ct], 0, 0, 0);
        }
    }
#pragma unroll
    for (int ct = 0; ct < 4; ct++) {
#pragma unroll
        for (int r = 0; r < 4; r++) {
            int node = nb + q * 4 + r;
            if (node < n) {
                float v = fmaxf(acc2[ct][r], 0.f);
                hbout[(size_t)node * 64 + ct * 16 + m] = f2bf(v);
            }
        }
    }
}

// ---------- MFMA final ----------
__global__ __launch_bounds__(256) void final_kernel(const ushort_t* __restrict__ xb,
                                                    const ushort_t* __restrict__ h1b,
                                                    const ushort_t* __restrict__ h2b,
                                                    const ushort_t* __restrict__ h3b,
                                                    const ushort_t* __restrict__ linf,
                                                    const float* __restrict__ lin_b,
                                                    float* __restrict__ out, int ntiles) {
    int tid = threadIdx.x;
    int w = tid >> 6, lane = tid & 63, m = lane & 15, q = lane >> 4;
    int tile = blockIdx.x * 4 + w;
    if (tile >= ntiles) return;
    int nb = tile * 16;
    const ushort_t* segs[4] = {xb, h1b, h2b, h3b};
    f32x4 acc[4];
#pragma unroll
    for (int ct = 0; ct < 4; ct++) {
        int col = ct * 16 + m;
        float bv = (col < HID) ? lin_b[col] : 0.f;
        acc[ct] = (f32x4){bv, bv, bv, bv};
    }
#pragma unroll
    for (int ks = 0; ks < 8; ks++) {
        const ushort_t* p = segs[ks >> 1];
        bf16x8 a = *(const bf16x8*)(p + (size_t)(nb + m) * 64 + (ks & 1) * 32 + q * 8);
#pragma unroll
        for (int ct = 0; ct < 4; ct++) {
            bf16x8 b = *(const bf16x8*)(linf + ((size_t)(ct * 8 + ks) * 64 + lane) * 8);
            acc[ct] = __builtin_amdgcn_mfma_f32_16x16x32_bf16(a, b, acc[ct], 0, 0, 0);
        }
    }
#pragma unroll
    for (int ct = 0; ct < 4; ct++) {
        int col = ct * 16 + m;
        if (col < HID) {
#pragma unroll
            for (int r = 0; r < 4; r++)
                out[(size_t)(nb + q * 4 + r) * HID + col] = acc[ct][r];
        }
    }
}

extern "C" void kernel_launch(void* const* d_in, const int* in_sizes, int n_in,
                              void* d_out, int out_size, void* d_ws, size_t ws_size,
                              hipStream_t stream) {
    const float* x     = (const float*)d_in[0];
    const int*   ei    = (const int*)d_in[1];
    const float* w1    = (const float*)d_in[2];
    const float* b1    = (const float*)d_in[3];
    const float* w2    = (const float*)d_in[4];
    const float* b2    = (const float*)d_in[5];
    const float* eps   = (const float*)d_in[6];
    const float* lin_w = (const float*)d_in[7];
    const float* lin_b = (const float*)d_in[8];
    float* out = (float*)d_out;

    const int N = in_sizes[0] / HID;       // 100000
    const int E = in_sizes[1] / 2;         // 3200000
    const int* src = ei;
    const int* dst = ei + E;

    const int NBIN = (N + 255) / 256;      // 391

    // ---- workspace layout (16B-aligned blocks) ----
    char* p = (char*)d_ws;
    ushort_t* xb  = (ushort_t*)p;  p += (size_t)N * 64 * 2;
    ushort_t* zb  = (ushort_t*)p;  p += (size_t)N * 64 * 2;
    ushort_t* h1b = (ushort_t*)p;  p += (size_t)N * 64 * 2;
    ushort_t* h2b = (ushort_t*)p;  p += (size_t)N * 64 * 2;
    ushort_t* h3b = (ushort_t*)p;  p += (size_t)N * 64 * 2;
    ushort_t* w1f = (ushort_t*)p;  p += 3 * 14 * 512 * 2;
    ushort_t* w2f = (ushort_t*)p;  p += 3 * 16 * 512 * 2;
    ushort_t* linf= (ushort_t*)p;  p += 32 * 512 * 2;
    int* ghist    = (int*)p;       p += 528 * 4;
    int* binstart = (int*)p;       p += 528 * 4;
    int* gcur     = (int*)p;       p += 528 * 4;
    int* nrs      = (int*)p;       p += (size_t)(N + 4) * 4;
    uint_t* packed = (uint_t*)p;   p += (size_t)E * 4;
    int* srcsorted = (int*)p;

    ushort_t* hbs[4] = {xb, h1b, h2b, h3b};

    const int BLK = 256;
    const int NP1 = (E + P1_CHUNK - 1) / P1_CHUNK;   // 391
    dim3 blk(BLK);
    dim3 grid_agg(((size_t)N * 64 + BLK - 1) / BLK);

    // ---- CSR build (two-pass radix) + converters ----
    hipMemsetAsync(ghist, 0, 512 * sizeof(int), stream);
    bhist_kernel<<<NP1, blk, 0, stream>>>(dst, ghist, E);
    bscan_kernel<<<1, blk, 0, stream>>>(ghist, binstart, gcur, nrs, NBIN, N, E);
    pass1_kernel<<<NP1, blk, 0, stream>>>(src, dst, gcur, packed, E);
    pass2_kernel<<<NBIN, blk, 0, stream>>>(packed, binstart, srcsorted, nrs, N);
    conv_x_kernel<<<(N * 16 + BLK - 1) / BLK, blk, 0, stream>>>(x, xb, N);
    conv_w_kernel<<<(122 * 64 + BLK - 1) / BLK, blk, 0, stream>>>(w1, w2, lin_w, w1f, w2f, linf);

    // ---- layers ----
    const int NBUCK = (N + 63) / 64;
    for (int l = 0; l < 3; l++) {
        agg_kernel<<<grid_agg, blk, 0, stream>>>(hbs[l], nrs, srcsorted, eps + l, zb, N);
        mlp_kernel<<<NBUCK, blk, 0, stream>>>(zb,
                                              w1f + (size_t)l * 14 * 512,
                                              b1 + (size_t)l * HID2,
                                              w2f + (size_t)l * 16 * 512,
                                              b2 + (size_t)l * HID,
                                              hbs[l + 1], N);
    }
    final_kernel<<<(6250 + 3) / 4 + 1, blk, 0, stream>>>(xb, h1b, h2b, h3b, linf, lin_b,
                                                         out, (N + 15) / 16);
}

// Round 7
// 410.431 us; speedup vs baseline: 8.7744x; 1.0181x over previous
//
#include <hip/hip_runtime.h>

#define HID 52
#define HID2 104
#define P1_CHUNK 8192
#define NBIN_MAX 512      // bins of 256 nodes; N <= 131072

typedef unsigned short ushort_t;
typedef unsigned int uint_t;
typedef short bf16x8 __attribute__((ext_vector_type(8)));
typedef float f32x4 __attribute__((ext_vector_type(4)));
typedef float f32x2 __attribute__((ext_vector_type(2)));

__device__ __forceinline__ ushort_t f2bf(float f) {
    union { float f; uint_t u; } c; c.f = f;
    uint_t u = c.u + 0x7FFFu + ((c.u >> 16) & 1u);   // RNE
    return (ushort_t)(u >> 16);
}
__device__ __forceinline__ float bflo(uint_t u) {
    union { uint_t u; float f; } c; c.u = u << 16; return c.f;
}
__device__ __forceinline__ float bfhi(uint_t u) {
    union { uint_t u; float f; } c; c.u = u & 0xFFFF0000u; return c.f;
}
__device__ __forceinline__ f32x2 unpk(uint_t u) {
    return (f32x2){bflo(u), bfhi(u)};
}

// ---------- two-pass dst-radix CSR build ----------

__global__ __launch_bounds__(256) void bhist_kernel(const int* __restrict__ dst,
                                                    int* __restrict__ ghist, int E) {
    __shared__ int lh[NBIN_MAX];
    int tid = threadIdx.x;
    lh[tid] = 0; lh[tid + 256] = 0;
    __syncthreads();
    int base = blockIdx.x * P1_CHUNK;
    int cend = min(P1_CHUNK, E - base);
    for (int i = tid; i < cend; i += 256) atomicAdd(&lh[dst[base + i] >> 8], 1);
    __syncthreads();
    int c = lh[tid];       if (c) atomicAdd(&ghist[tid], c);
    c = lh[tid + 256];     if (c) atomicAdd(&ghist[tid + 256], c);
}

__global__ __launch_bounds__(256) void bscan_kernel(const int* __restrict__ ghist,
                                                    int* __restrict__ binstart,
                                                    int* __restrict__ gcur,
                                                    int NBIN, int E) {
    __shared__ int c[NBIN_MAX];
    __shared__ int ps[256];
    int tid = threadIdx.x;
    int b0 = 2 * tid, b1 = 2 * tid + 1;
    c[b0] = ghist[b0]; c[b1] = ghist[b1];
    __syncthreads();
    int pair = c[b0] + c[b1];
    ps[tid] = pair;
    __syncthreads();
    for (int off = 1; off < 256; off <<= 1) {
        int t = (tid >= off) ? ps[tid - off] : 0;
        __syncthreads();
        ps[tid] += t;
        __syncthreads();
    }
    int ex = ps[tid] - pair;
    binstart[b0] = ex;        gcur[b0] = ex;
    binstart[b1] = ex + c[b0]; gcur[b1] = ex + c[b0];
    if (tid == 0) binstart[NBIN] = E;
}

// pass 1: bin-partition edges with LDS staging; coalesced run writes
__global__ __launch_bounds__(256) void pass1_kernel(const int* __restrict__ src,
                                                    const int* __restrict__ dst,
                                                    int* __restrict__ gcur,
                                                    uint_t* __restrict__ packed, int E) {
    __shared__ uint_t stage[P1_CHUNK];
    __shared__ ushort_t sbin[P1_CHUNK];
    __shared__ int cnt[NBIN_MAX];
    __shared__ int sst[NBIN_MAX];
    __shared__ int curs[NBIN_MAX];
    __shared__ int gbase[NBIN_MAX];
    __shared__ int ps[256];
    int tid = threadIdx.x;
    int base = blockIdx.x * P1_CHUNK;
    int cend = min(P1_CHUNK, E - base);
    cnt[tid] = 0; cnt[tid + 256] = 0;
    __syncthreads();
    for (int i = tid; i < cend; i += 256) atomicAdd(&cnt[dst[base + i] >> 8], 1);
    __syncthreads();
    int b0 = 2 * tid, b1 = 2 * tid + 1;
    int c0 = cnt[b0], c1 = cnt[b1];
    int pair = c0 + c1;
    ps[tid] = pair;
    __syncthreads();
    for (int off = 1; off < 256; off <<= 1) {
        int t = (tid >= off) ? ps[tid - off] : 0;
        __syncthreads();
        ps[tid] += t;
        __syncthreads();
    }
    int ex = ps[tid] - pair;
    sst[b0] = ex;       curs[b0] = ex;
    sst[b1] = ex + c0;  curs[b1] = ex + c0;
    gbase[b0] = c0 ? atomicAdd(&gcur[b0], c0) : 0;
    gbase[b1] = c1 ? atomicAdd(&gcur[b1], c1) : 0;
    __syncthreads();
    for (int i = tid; i < cend; i += 256) {
        int d = dst[base + i];
        int s = src[base + i];
        int b = d >> 8;
        int pos = atomicAdd(&curs[b], 1);
        stage[pos] = ((uint_t)s << 8) | (uint_t)(d & 255);
        sbin[pos] = (ushort_t)b;
    }
    __syncthreads();
    for (int i = tid; i < cend; i += 256) {
        int b = sbin[i];
        packed[gbase[b] + (i - sst[b])] = stage[i];
    }
}

// pass 2: per-bin counting sort -> srcsorted (node runs padded to x16 with zero-row idx N)
// emits nrs[v] (padded start) and ndeg[v] (padded count, multiple of 16)
__global__ __launch_bounds__(256) void pass2_kernel(const uint_t* __restrict__ packed,
                                                    const int* __restrict__ binstart,
                                                    int* __restrict__ srcsorted,
                                                    int* __restrict__ nrs,
                                                    int* __restrict__ ndeg, int N) {
    __shared__ int ncnt[256];
    __shared__ int ps[256];
    __shared__ int curs[256];
    int b = blockIdx.x;
    int beg = binstart[b], end = binstart[b + 1];
    int obase = beg + b * 4096;          // padded-region base (4096 slack per bin)
    int tid = threadIdx.x;
    ncnt[tid] = 0;
    __syncthreads();
    for (int i = beg + tid; i < end; i += 256) atomicAdd(&ncnt[packed[i] & 255u], 1);
    __syncthreads();
    int v = ncnt[tid];
    int pv = (v + 15) & ~15;
    ps[tid] = pv;
    __syncthreads();
    for (int off = 1; off < 256; off <<= 1) {
        int t = (tid >= off) ? ps[tid - off] : 0;
        __syncthreads();
        ps[tid] += t;
        __syncthreads();
    }
    int start = obase + ps[tid] - pv;
    int node = b * 256 + tid;
    if (node < N) { nrs[node] = start; ndeg[node] = pv; }
    curs[tid] = start;
    __syncthreads();
    for (int i = beg + tid; i < end; i += 256) {
        uint_t p = packed[i];
        int pos = atomicAdd(&curs[p & 255u], 1);
        srcsorted[pos] = (int)(p >> 8);
    }
    __syncthreads();
    for (int i = start + v; i < start + pv; i++) srcsorted[i] = N;   // zero-row pads
}

// ---------- converters ----------

__global__ void conv_x_kernel(const float* __restrict__ x, ushort_t* __restrict__ xb, int n) {
    int t = blockIdx.x * 256 + threadIdx.x;
    if (t >= n * 16) return;
    int node = t >> 4, p = t & 15;
    int c0 = p * 4;
    ushort_t o[4];
#pragma unroll
    for (int j = 0; j < 4; j++) {
        int c = c0 + j;
        o[j] = (c < HID) ? f2bf(x[(size_t)node * HID + c]) : 0;
    }
    uint_t u0 = (uint_t)o[0] | ((uint_t)o[1] << 16);
    uint_t u1 = (uint_t)o[2] | ((uint_t)o[3] << 16);
    *(uint2*)(xb + (size_t)node * 64 + c0) = make_uint2(u0, u1);
}

// zero row N of the four gatherable tables (pad target)
__global__ void zero_pad_rows_kernel(ushort_t* xb, ushort_t* h1b, ushort_t* h2b,
                                     ushort_t* h3b, int N) {
    int t = threadIdx.x;
    ushort_t* arr = (t < 64) ? xb : (t < 128) ? h1b : (t < 192) ? h2b : h3b;
    arr[(size_t)N * 64 + (t & 63)] = 0;
}

__global__ void conv_w_kernel(const float* __restrict__ w1, const float* __restrict__ w2,
                              const float* __restrict__ lin_w,
                              ushort_t* __restrict__ w1f, ushort_t* __restrict__ w2f,
                              ushort_t* __restrict__ linf) {
    int t = blockIdx.x * 256 + threadIdx.x;
    int gid = t >> 6, lane = t & 63;
    if (gid >= 122) return;
    int m = lane & 15, q = lane >> 4;
    ushort_t o[8];
    ushort_t* dstp;
    if (gid < 42) {
        int l = gid / 14, r = gid % 14, ct = r >> 1, ks = r & 1;
        int nn = ct * 16 + m;
#pragma unroll
        for (int j = 0; j < 8; j++) {
            int k = ks * 32 + q * 8 + j;
            o[j] = (k < HID && nn < HID2) ? f2bf(w1[((size_t)l * HID + k) * HID2 + nn]) : 0;
        }
        dstp = w1f + ((size_t)(l * 14 + ct * 2 + ks) * 64 + lane) * 8;
    } else if (gid < 90) {
        int g2 = gid - 42, l = g2 / 16, r = g2 % 16, ct = r >> 2, ks = r & 3;
        int nn = ct * 16 + m;
#pragma unroll
        for (int j = 0; j < 8; j++) {
            int k = ks * 32 + q * 8 + j;
            o[j] = (k < HID2 && nn < HID) ? f2bf(w2[((size_t)l * HID2 + k) * HID + nn]) : 0;
        }
        dstp = w2f + ((size_t)(l * 16 + ct * 4 + ks) * 64 + lane) * 8;
    } else {
        int g2 = gid - 90, ct = g2 >> 3, ks = g2 & 7;
        int nn = ct * 16 + m;
#pragma unroll
        for (int j = 0; j < 8; j++) {
            int kg = ks * 32 + q * 8 + j;
            int seg = kg >> 6, kk = kg & 63;
            o[j] = (kk < HID && nn < HID) ? f2bf(lin_w[((size_t)seg * HID + kk) * HID + nn]) : 0;
        }
        dstp = linf + ((size_t)(ct * 8 + ks) * 64 + lane) * 8;
    }
    uint4 u;
    u.x = (uint_t)o[0] | ((uint_t)o[1] << 16);
    u.y = (uint_t)o[2] | ((uint_t)o[3] << 16);
    u.z = (uint_t)o[4] | ((uint_t)o[5] << 16);
    u.w = (uint_t)o[6] | ((uint_t)o[7] << 16);
    *(uint4*)dstp = u;
}

// ---------- aggregation: wave per node, padded edge runs, dual loads in flight ----------
__global__ __launch_bounds__(256) void agg_kernel(const ushort_t* __restrict__ hb,
                                                  const int* __restrict__ nrs,
                                                  const int* __restrict__ ndeg,
                                                  const int* __restrict__ srcsorted,
                                                  const float* __restrict__ eps,
                                                  ushort_t* __restrict__ zb, int n) {
    int wid = (blockIdx.x * blockDim.x + threadIdx.x) >> 6;
    if (wid >= n) return;
    int lane = threadIdx.x & 63;
    int g = lane >> 3, sub = lane & 7;
    int beg = nrs[wid];
    int total = ndeg[wid];               // multiple of 16 (pads -> zero row)
    const ushort_t* hsub = hb + sub * 8;

    f32x2 A0 = {0,0}, A1 = {0,0}, A2 = {0,0}, A3 = {0,0};
    f32x2 B0 = {0,0}, B1 = {0,0}, B2 = {0,0}, B3 = {0,0};
    for (int b = 0; b < total; b += 64) {
        int cnt = min(64, total - b);    // multiple of 16
        int idx = (lane < cnt) ? srcsorted[beg + b + lane] : 0;
        int jmax = cnt >> 3;             // even
        for (int j = 0; j < jmax; j += 2) {
            int s0 = __shfl(idx, (j << 3) | g);
            int s1 = __shfl(idx, ((j + 1) << 3) | g);
            uint4 v0 = *(const uint4*)(hsub + (size_t)s0 * 64);
            uint4 v1 = *(const uint4*)(hsub + (size_t)s1 * 64);
            A0 += unpk(v0.x); A1 += unpk(v0.y); A2 += unpk(v0.z); A3 += unpk(v0.w);
            B0 += unpk(v1.x); B1 += unpk(v1.y); B2 += unpk(v1.z); B3 += unpk(v1.w);
        }
    }
    A0 += B0; A1 += B1; A2 += B2; A3 += B3;
    float a0 = A0.x, a1 = A0.y, a2 = A1.x, a3 = A1.y;
    float a4 = A2.x, a5 = A2.y, a6 = A3.x, a7 = A3.y;
#pragma unroll
    for (int msk = 8; msk <= 32; msk <<= 1) {
        a0 += __shfl_xor(a0, msk); a1 += __shfl_xor(a1, msk);
        a2 += __shfl_xor(a2, msk); a3 += __shfl_xor(a3, msk);
        a4 += __shfl_xor(a4, msk); a5 += __shfl_xor(a5, msk);
        a6 += __shfl_xor(a6, msk); a7 += __shfl_xor(a7, msk);
    }
    if (lane < 8) {
        float sc = 1.0f + eps[0];
        uint4 sv = *(const uint4*)(hb + (size_t)wid * 64 + lane * 8);
        float o0 = fmaf(sc, bflo(sv.x), a0), o1 = fmaf(sc, bfhi(sv.x), a1);
        float o2 = fmaf(sc, bflo(sv.y), a2), o3 = fmaf(sc, bfhi(sv.y), a3);
        float o4 = fmaf(sc, bflo(sv.z), a4), o5 = fmaf(sc, bfhi(sv.z), a5);
        float o6 = fmaf(sc, bflo(sv.w), a6), o7 = fmaf(sc, bfhi(sv.w), a7);
        uint4 u;
        u.x = (uint_t)f2bf(o0) | ((uint_t)f2bf(o1) << 16);
        u.y = (uint_t)f2bf(o2) | ((uint_t)f2bf(o3) << 16);
        u.z = (uint_t)f2bf(o4) | ((uint_t)f2bf(o5) << 16);
        u.w = (uint_t)f2bf(o6) | ((uint_t)f2bf(o7) << 16);
        *(uint4*)(zb + (size_t)wid * 64 + lane * 8) = u;
    }
}

// ---------- MFMA fused 2-layer MLP ----------
#define HSTRIDE 136
__global__ __launch_bounds__(256) void mlp_kernel(const ushort_t* __restrict__ zb,
                                                  const ushort_t* __restrict__ w1f,
                                                  const float* __restrict__ b1,
                                                  const ushort_t* __restrict__ w2f,
                                                  const float* __restrict__ b2,
                                                  ushort_t* __restrict__ hbout, int n) {
    __shared__ ushort_t hid[64 * HSTRIDE];
    int tid = threadIdx.x;
    int w = tid >> 6, lane = tid & 63, m = lane & 15, q = lane >> 4;
    for (int i = tid; i < 64 * 32; i += 256) {
        int r = i >> 5, c = HID2 + (i & 31);
        hid[r * HSTRIDE + c] = 0;
    }
    __syncthreads();

    int nb = blockIdx.x * 64 + w * 16;
    f32x4 acc1[7];
#pragma unroll
    for (int ct = 0; ct < 7; ct++) {
        int col = ct * 16 + m;
        float bv = (col < HID2) ? b1[col] : 0.f;
        acc1[ct] = (f32x4){bv, bv, bv, bv};
    }
    int anode = min(nb + m, n - 1);
#pragma unroll
    for (int ks = 0; ks < 2; ks++) {
        bf16x8 a = *(const bf16x8*)(zb + (size_t)anode * 64 + ks * 32 + q * 8);
#pragma unroll
        for (int ct = 0; ct < 7; ct++) {
            bf16x8 b = *(const bf16x8*)(w1f + ((size_t)(ct * 2 + ks) * 64 + lane) * 8);
            acc1[ct] = __builtin_amdgcn_mfma_f32_16x16x32_bf16(a, b, acc1[ct], 0, 0, 0);
        }
    }
#pragma unroll
    for (int ct = 0; ct < 7; ct++) {
#pragma unroll
        for (int r = 0; r < 4; r++) {
            float v = fmaxf(acc1[ct][r], 0.f);
            int row = w * 16 + q * 4 + r;
            hid[row * HSTRIDE + ct * 16 + m] = f2bf(v);
        }
    }
    f32x4 acc2[4];
#pragma unroll
    for (int ct = 0; ct < 4; ct++) {
        int col = ct * 16 + m;
        float bv = (col < HID) ? b2[col] : 0.f;
        acc2[ct] = (f32x4){bv, bv, bv, bv};
    }
#pragma unroll
    for (int ks = 0; ks < 4; ks++) {
        bf16x8 a = *(const bf16x8*)&hid[(w * 16 + m) * HSTRIDE + ks * 32 + q * 8];
#pragma unroll
        for (int ct = 0; ct < 4; ct++) {
            bf16x8 b = *(const bf16x8*)(w2f + ((size_t)(ct * 4 + ks) * 64 + lane) * 8);
            acc2[ct] = __builtin_amdgcn_mfma_f32_16x16x32_bf16(a, b, acc2[ct], 0, 0, 0);
        }
    }
#pragma unroll
    for (int ct = 0; ct < 4; ct++) {
#pragma unroll
        for (int r = 0; r < 4; r++) {
            int node = nb + q * 4 + r;
            if (node < n) {
                float v = fmaxf(acc2[ct][r], 0.f);
                hbout[(size_t)node * 64 + ct * 16 + m] = f2bf(v);
            }
        }
    }
}

// ---------- MFMA final ----------
__global__ __launch_bounds__(256) void final_kernel(const ushort_t* __restrict__ xb,
                                                    const ushort_t* __restrict__ h1b,
                                                    const ushort_t* __restrict__ h2b,
                                                    const ushort_t* __restrict__ h3b,
                                                    const ushort_t* __restrict__ linf,
                                                    const float* __restrict__ lin_b,
                                                    float* __restrict__ out, int ntiles) {
    int tid = threadIdx.x;
    int w = tid >> 6, lane = tid & 63, m = lane & 15, q = lane >> 4;
    int tile = blockIdx.x * 4 + w;
    if (tile >= ntiles) return;
    int nb = tile * 16;
    const ushort_t* segs[4] = {xb, h1b, h2b, h3b};
    f32x4 acc[4];
#pragma unroll
    for (int ct = 0; ct < 4; ct++) {
        int col = ct * 16 + m;
        float bv = (col < HID) ? lin_b[col] : 0.f;
        acc[ct] = (f32x4){bv, bv, bv, bv};
    }
#pragma unroll
    for (int ks = 0; ks < 8; ks++) {
        const ushort_t* p = segs[ks >> 1];
        bf16x8 a = *(const bf16x8*)(p + (size_t)(nb + m) * 64 + (ks & 1) * 32 + q * 8);
#pragma unroll
        for (int ct = 0; ct < 4; ct++) {
            bf16x8 b = *(const bf16x8*)(linf + ((size_t)(ct * 8 + ks) * 64 + lane) * 8);
            acc[ct] = __builtin_amdgcn_mfma_f32_16x16x32_bf16(a, b, acc[ct], 0, 0, 0);
        }
    }
#pragma unroll
    for (int ct = 0; ct < 4; ct++) {
        int col = ct * 16 + m;
        if (col < HID) {
#pragma unroll
            for (int r = 0; r < 4; r++)
                out[(size_t)(nb + q * 4 + r) * HID + col] = acc[ct][r];
        }
    }
}

extern "C" void kernel_launch(void* const* d_in, const int* in_sizes, int n_in,
                              void* d_out, int out_size, void* d_ws, size_t ws_size,
                              hipStream_t stream) {
    const float* x     = (const float*)d_in[0];
    const int*   ei    = (const int*)d_in[1];
    const float* w1    = (const float*)d_in[2];
    const float* b1    = (const float*)d_in[3];
    const float* w2    = (const float*)d_in[4];
    const float* b2    = (const float*)d_in[5];
    const float* eps   = (const float*)d_in[6];
    const float* lin_w = (const float*)d_in[7];
    const float* lin_b = (const float*)d_in[8];
    float* out = (float*)d_out;

    const int N = in_sizes[0] / HID;       // 100000
    const int E = in_sizes[1] / 2;         // 3200000
    const int* src = ei;
    const int* dst = ei + E;

    const int NBIN = (N + 255) / 256;      // 391

    // ---- workspace layout (16B-aligned blocks); bf16 tables have extra zero row N ----
    char* p = (char*)d_ws;
    const size_t ROWS = (size_t)(N + 1) * 64 * 2;
    ushort_t* xb  = (ushort_t*)p;  p += ROWS;
    ushort_t* zb  = (ushort_t*)p;  p += ROWS;
    ushort_t* h1b = (ushort_t*)p;  p += ROWS;
    ushort_t* h2b = (ushort_t*)p;  p += ROWS;
    ushort_t* h3b = (ushort_t*)p;  p += ROWS;
    ushort_t* w1f = (ushort_t*)p;  p += 3 * 14 * 512 * 2;
    ushort_t* w2f = (ushort_t*)p;  p += 3 * 16 * 512 * 2;
    ushort_t* linf= (ushort_t*)p;  p += 32 * 512 * 2;
    int* ghist    = (int*)p;       p += 528 * 4;
    int* binstart = (int*)p;       p += 528 * 4;
    int* gcur     = (int*)p;       p += 528 * 4;
    int* nrs      = (int*)p;       p += (size_t)(N + 4) * 4;
    int* ndeg     = (int*)p;       p += (size_t)(N + 4) * 4;
    uint_t* packed = (uint_t*)p;   p += (size_t)E * 4;
    int* srcsorted = (int*)p;      // E + NBIN*4096 entries

    ushort_t* hbs[4] = {xb, h1b, h2b, h3b};

    const int BLK = 256;
    const int NP1 = (E + P1_CHUNK - 1) / P1_CHUNK;   // 391
    dim3 blk(BLK);
    dim3 grid_agg(((size_t)N * 64 + BLK - 1) / BLK);

    // ---- CSR build (two-pass radix, padded runs) + converters ----
    hipMemsetAsync(ghist, 0, 512 * sizeof(int), stream);
    bhist_kernel<<<NP1, blk, 0, stream>>>(dst, ghist, E);
    bscan_kernel<<<1, blk, 0, stream>>>(ghist, binstart, gcur, NBIN, E);
    pass1_kernel<<<NP1, blk, 0, stream>>>(src, dst, gcur, packed, E);
    pass2_kernel<<<NBIN, blk, 0, stream>>>(packed, binstart, srcsorted, nrs, ndeg, N);
    conv_x_kernel<<<(N * 16 + BLK - 1) / BLK, blk, 0, stream>>>(x, xb, N);
    zero_pad_rows_kernel<<<1, 256, 0, stream>>>(xb, h1b, h2b, h3b, N);
    conv_w_kernel<<<(122 * 64 + BLK - 1) / BLK, blk, 0, stream>>>(w1, w2, lin_w, w1f, w2f, linf);

    // ---- layers ----
    const int NBUCK = (N + 63) / 64;
    for (int l = 0; l < 3; l++) {
        agg_kernel<<<grid_agg, blk, 0, stream>>>(hbs[l], nrs, ndeg, srcsorted, eps + l, zb, N);
        mlp_kernel<<<NBUCK, blk, 0, stream>>>(zb,
                                              w1f + (size_t)l * 14 * 512,
                                              b1 + (size_t)l * HID2,
                                              w2f + (size_t)l * 16 * 512,
                                              b2 + (size_t)l * HID,
                                              hbs[l + 1], N);
    }
    final_kernel<<<(6250 + 3) / 4 + 1, blk, 0, stream>>>(xb, h1b, h2b, h3b, linf, lin_b,
                                                         out, (N + 15) / 16);
}

// Round 8
// 403.812 us; speedup vs baseline: 8.9182x; 1.0164x over previous
//
#include <hip/hip_runtime.h>

#define HID 52
#define HID2 104
#define P1_CHUNK 8192
#define NBIN_MAX 512      // bins of 256 nodes; N <= 131072

typedef unsigned short ushort_t;
typedef unsigned int uint_t;
typedef short bf16x8 __attribute__((ext_vector_type(8)));
typedef float f32x4 __attribute__((ext_vector_type(4)));
typedef float f32x2 __attribute__((ext_vector_type(2)));

__device__ __forceinline__ ushort_t f2bf(float f) {
    union { float f; uint_t u; } c; c.f = f;
    uint_t u = c.u + 0x7FFFu + ((c.u >> 16) & 1u);   // RNE
    return (ushort_t)(u >> 16);
}
__device__ __forceinline__ float bflo(uint_t u) {
    union { uint_t u; float f; } c; c.u = u << 16; return c.f;
}
__device__ __forceinline__ float bfhi(uint_t u) {
    union { uint_t u; float f; } c; c.u = u & 0xFFFF0000u; return c.f;
}
__device__ __forceinline__ f32x2 unpk(uint_t u) {
    return (f32x2){bflo(u), bfhi(u)};
}

// ---------- two-pass dst-radix CSR build ----------

__global__ __launch_bounds__(256) void bhist_kernel(const int* __restrict__ dst,
                                                    int* __restrict__ ghist, int E) {
    __shared__ int lh[NBIN_MAX];
    int tid = threadIdx.x;
    lh[tid] = 0; lh[tid + 256] = 0;
    __syncthreads();
    int base = blockIdx.x * P1_CHUNK;
    int cend = min(P1_CHUNK, E - base);
    for (int i = tid; i < cend; i += 256) atomicAdd(&lh[dst[base + i] >> 8], 1);
    __syncthreads();
    int c = lh[tid];       if (c) atomicAdd(&ghist[tid], c);
    c = lh[tid + 256];     if (c) atomicAdd(&ghist[tid + 256], c);
}

__global__ __launch_bounds__(256) void bscan_kernel(const int* __restrict__ ghist,
                                                    int* __restrict__ binstart,
                                                    int* __restrict__ gcur,
                                                    int NBIN, int E) {
    __shared__ int c[NBIN_MAX];
    __shared__ int ps[256];
    int tid = threadIdx.x;
    int b0 = 2 * tid, b1 = 2 * tid + 1;
    c[b0] = ghist[b0]; c[b1] = ghist[b1];
    __syncthreads();
    int pair = c[b0] + c[b1];
    ps[tid] = pair;
    __syncthreads();
    for (int off = 1; off < 256; off <<= 1) {
        int t = (tid >= off) ? ps[tid - off] : 0;
        __syncthreads();
        ps[tid] += t;
        __syncthreads();
    }
    int ex = ps[tid] - pair;
    binstart[b0] = ex;        gcur[b0] = ex;
    binstart[b1] = ex + c[b0]; gcur[b1] = ex + c[b0];
    if (tid == 0) binstart[NBIN] = E;
}

// pass 1: bin-partition edges with LDS staging; coalesced run writes
__global__ __launch_bounds__(256) void pass1_kernel(const int* __restrict__ src,
                                                    const int* __restrict__ dst,
                                                    int* __restrict__ gcur,
                                                    uint_t* __restrict__ packed, int E) {
    __shared__ uint_t stage[P1_CHUNK];
    __shared__ ushort_t sbin[P1_CHUNK];
    __shared__ int cnt[NBIN_MAX];
    __shared__ int sst[NBIN_MAX];
    __shared__ int curs[NBIN_MAX];
    __shared__ int gbase[NBIN_MAX];
    __shared__ int ps[256];
    int tid = threadIdx.x;
    int base = blockIdx.x * P1_CHUNK;
    int cend = min(P1_CHUNK, E - base);
    cnt[tid] = 0; cnt[tid + 256] = 0;
    __syncthreads();
    for (int i = tid; i < cend; i += 256) atomicAdd(&cnt[dst[base + i] >> 8], 1);
    __syncthreads();
    int b0 = 2 * tid, b1 = 2 * tid + 1;
    int c0 = cnt[b0], c1 = cnt[b1];
    int pair = c0 + c1;
    ps[tid] = pair;
    __syncthreads();
    for (int off = 1; off < 256; off <<= 1) {
        int t = (tid >= off) ? ps[tid - off] : 0;
        __syncthreads();
        ps[tid] += t;
        __syncthreads();
    }
    int ex = ps[tid] - pair;
    sst[b0] = ex;       curs[b0] = ex;
    sst[b1] = ex + c0;  curs[b1] = ex + c0;
    gbase[b0] = c0 ? atomicAdd(&gcur[b0], c0) : 0;
    gbase[b1] = c1 ? atomicAdd(&gcur[b1], c1) : 0;
    __syncthreads();
    for (int i = tid; i < cend; i += 256) {
        int d = dst[base + i];
        int s = src[base + i];
        int b = d >> 8;
        int pos = atomicAdd(&curs[b], 1);
        stage[pos] = ((uint_t)s << 8) | (uint_t)(d & 255);
        sbin[pos] = (ushort_t)b;
    }
    __syncthreads();
    for (int i = tid; i < cend; i += 256) {
        int b = sbin[i];
        packed[gbase[b] + (i - sst[b])] = stage[i];
    }
}

// pass 2: per-bin counting sort -> srcsorted (node runs padded to x16 with zero-row idx N)
__global__ __launch_bounds__(256) void pass2_kernel(const uint_t* __restrict__ packed,
                                                    const int* __restrict__ binstart,
                                                    int* __restrict__ srcsorted,
                                                    int* __restrict__ nrs,
                                                    int* __restrict__ ndeg, int N) {
    __shared__ int ncnt[256];
    __shared__ int ps[256];
    __shared__ int curs[256];
    int b = blockIdx.x;
    int beg = binstart[b], end = binstart[b + 1];
    int obase = beg + b * 4096;          // padded-region base (4096 slack per bin)
    int tid = threadIdx.x;
    ncnt[tid] = 0;
    __syncthreads();
    for (int i = beg + tid; i < end; i += 256) atomicAdd(&ncnt[packed[i] & 255u], 1);
    __syncthreads();
    int v = ncnt[tid];
    int pv = (v + 15) & ~15;
    ps[tid] = pv;
    __syncthreads();
    for (int off = 1; off < 256; off <<= 1) {
        int t = (tid >= off) ? ps[tid - off] : 0;
        __syncthreads();
        ps[tid] += t;
        __syncthreads();
    }
    int start = obase + ps[tid] - pv;
    int node = b * 256 + tid;
    if (node < N) { nrs[node] = start; ndeg[node] = pv; }
    curs[tid] = start;
    __syncthreads();
    for (int i = beg + tid; i < end; i += 256) {
        uint_t p = packed[i];
        int pos = atomicAdd(&curs[p & 255u], 1);
        srcsorted[pos] = (int)(p >> 8);
    }
    __syncthreads();
    for (int i = start + v; i < start + pv; i++) srcsorted[i] = N;   // zero-row pads
}

// ---------- fused setup: conv_x + zero pad rows + conv_w + zero ghist ----------
__global__ __launch_bounds__(256) void setup_kernel(const float* __restrict__ x,
                                                    const float* __restrict__ w1,
                                                    const float* __restrict__ w2,
                                                    const float* __restrict__ lin_w,
                                                    ushort_t* __restrict__ xb,
                                                    ushort_t* __restrict__ h1b,
                                                    ushort_t* __restrict__ h2b,
                                                    ushort_t* __restrict__ h3b,
                                                    ushort_t* __restrict__ w1f,
                                                    ushort_t* __restrict__ w2f,
                                                    ushort_t* __restrict__ linf,
                                                    int* __restrict__ ghist,
                                                    int n, int nxblk) {
    int blk = blockIdx.x;
    int tid = threadIdx.x;
    if (blk < nxblk) {
        // conv_x: fp32 [N][52] -> bf16 [N][64] padded
        int t = blk * 256 + tid;
        if (t >= n * 16) return;
        int node = t >> 4, pp = t & 15;
        int c0 = pp * 4;
        ushort_t o[4];
#pragma unroll
        for (int j = 0; j < 4; j++) {
            int c = c0 + j;
            o[j] = (c < HID) ? f2bf(x[(size_t)node * HID + c]) : 0;
        }
        uint_t u0 = (uint_t)o[0] | ((uint_t)o[1] << 16);
        uint_t u1 = (uint_t)o[2] | ((uint_t)o[3] << 16);
        *(uint2*)(xb + (size_t)node * 64 + c0) = make_uint2(u0, u1);
        return;
    }
    if (blk == nxblk) {
        // zero row N of gather tables + zero ghist
        ushort_t* arr = (tid < 64) ? xb : (tid < 128) ? h1b : (tid < 192) ? h2b : h3b;
        arr[(size_t)n * 64 + (tid & 63)] = 0;
        ghist[tid] = 0; ghist[tid + 256] = 0;
        return;
    }
    // conv_w
    int gid = (blk - nxblk - 1) * 4 + (tid >> 6);
    int lane = tid & 63;
    if (gid >= 122) return;
    int m = lane & 15, q = lane >> 4;
    ushort_t o[8];
    ushort_t* dstp;
    if (gid < 42) {
        int l = gid / 14, r = gid % 14, ct = r >> 1, ks = r & 1;
        int nn = ct * 16 + m;
#pragma unroll
        for (int j = 0; j < 8; j++) {
            int k = ks * 32 + q * 8 + j;
            o[j] = (k < HID && nn < HID2) ? f2bf(w1[((size_t)l * HID + k) * HID2 + nn]) : 0;
        }
        dstp = w1f + ((size_t)(l * 14 + ct * 2 + ks) * 64 + lane) * 8;
    } else if (gid < 90) {
        int g2 = gid - 42, l = g2 / 16, r = g2 % 16, ct = r >> 2, ks = r & 3;
        int nn = ct * 16 + m;
#pragma unroll
        for (int j = 0; j < 8; j++) {
            int k = ks * 32 + q * 8 + j;
            o[j] = (k < HID2 && nn < HID) ? f2bf(w2[((size_t)l * HID2 + k) * HID + nn]) : 0;
        }
        dstp = w2f + ((size_t)(l * 16 + ct * 4 + ks) * 64 + lane) * 8;
    } else {
        int g2 = gid - 90, ct = g2 >> 3, ks = g2 & 7;
        int nn = ct * 16 + m;
#pragma unroll
        for (int j = 0; j < 8; j++) {
            int kg = ks * 32 + q * 8 + j;
            int seg = kg >> 6, kk = kg & 63;
            o[j] = (kk < HID && nn < HID) ? f2bf(lin_w[((size_t)seg * HID + kk) * HID + nn]) : 0;
        }
        dstp = linf + ((size_t)(ct * 8 + ks) * 64 + lane) * 8;
    }
    uint4 u;
    u.x = (uint_t)o[0] | ((uint_t)o[1] << 16);
    u.y = (uint_t)o[2] | ((uint_t)o[3] << 16);
    u.z = (uint_t)o[4] | ((uint_t)o[5] << 16);
    u.w = (uint_t)o[6] | ((uint_t)o[7] << 16);
    *(uint4*)dstp = u;
}

// ---------- aggregation: wave/node, direct idx loads (no shfl), 4 rows in flight ----------
__global__ __launch_bounds__(256) void agg_kernel(const ushort_t* __restrict__ hb,
                                                  const int* __restrict__ nrs,
                                                  const int* __restrict__ ndeg,
                                                  const int* __restrict__ srcsorted,
                                                  const float* __restrict__ eps,
                                                  ushort_t* __restrict__ zb, int n) {
    int wid = (blockIdx.x * blockDim.x + threadIdx.x) >> 6;
    if (wid >= n) return;
    int lane = threadIdx.x & 63;
    int g = lane >> 3, sub = lane & 7;
    int beg = nrs[wid];
    int total = ndeg[wid];               // multiple of 16 (pads -> zero row N)
    const ushort_t* hsub = hb + sub * 8;
    const int* ss = srcsorted + beg + g; // group g's edge stream

    f32x2 A0 = {0,0}, A1 = {0,0}, A2 = {0,0}, A3 = {0,0};
    f32x2 B0 = {0,0}, B1 = {0,0}, B2 = {0,0}, B3 = {0,0};
    if (total > 0) {
        // prefetched idx for current iteration (reads beyond run land in slack, never used)
        int f0 = ss[0], f1 = ss[8], f2r = ss[16], f3r = ss[24];
        for (int b = 0; b < total; b += 32) {
            bool ok = (b + 16) < total;
            int e0 = f0, e1 = f1;
            int e2 = ok ? f2r : n;       // clamp to zero row
            int e3 = ok ? f3r : n;
            // prefetch next iteration's idx (in-bounds via +64 slack)
            f0 = ss[b + 32]; f1 = ss[b + 40]; f2r = ss[b + 48]; f3r = ss[b + 56];
            uint4 v0 = *(const uint4*)(hsub + (size_t)e0 * 64);
            uint4 v1 = *(const uint4*)(hsub + (size_t)e1 * 64);
            uint4 v2 = *(const uint4*)(hsub + (size_t)e2 * 64);
            uint4 v3 = *(const uint4*)(hsub + (size_t)e3 * 64);
            A0 += unpk(v0.x); A1 += unpk(v0.y); A2 += unpk(v0.z); A3 += unpk(v0.w);
            B0 += unpk(v1.x); B1 += unpk(v1.y); B2 += unpk(v1.z); B3 += unpk(v1.w);
            A0 += unpk(v2.x); A1 += unpk(v2.y); A2 += unpk(v2.z); A3 += unpk(v2.w);
            B0 += unpk(v3.x); B1 += unpk(v3.y); B2 += unpk(v3.z); B3 += unpk(v3.w);
        }
    }
    A0 += B0; A1 += B1; A2 += B2; A3 += B3;
    float a0 = A0.x, a1 = A0.y, a2 = A1.x, a3 = A1.y;
    float a4 = A2.x, a5 = A2.y, a6 = A3.x, a7 = A3.y;
#pragma unroll
    for (int msk = 8; msk <= 32; msk <<= 1) {
        a0 += __shfl_xor(a0, msk); a1 += __shfl_xor(a1, msk);
        a2 += __shfl_xor(a2, msk); a3 += __shfl_xor(a3, msk);
        a4 += __shfl_xor(a4, msk); a5 += __shfl_xor(a5, msk);
        a6 += __shfl_xor(a6, msk); a7 += __shfl_xor(a7, msk);
    }
    if (lane < 8) {
        float sc = 1.0f + eps[0];
        uint4 sv = *(const uint4*)(hb + (size_t)wid * 64 + lane * 8);
        float o0 = fmaf(sc, bflo(sv.x), a0), o1 = fmaf(sc, bfhi(sv.x), a1);
        float o2 = fmaf(sc, bflo(sv.y), a2), o3 = fmaf(sc, bfhi(sv.y), a3);
        float o4 = fmaf(sc, bflo(sv.z), a4), o5 = fmaf(sc, bfhi(sv.z), a5);
        float o6 = fmaf(sc, bflo(sv.w), a6), o7 = fmaf(sc, bfhi(sv.w), a7);
        uint4 u;
        u.x = (uint_t)f2bf(o0) | ((uint_t)f2bf(o1) << 16);
        u.y = (uint_t)f2bf(o2) | ((uint_t)f2bf(o3) << 16);
        u.z = (uint_t)f2bf(o4) | ((uint_t)f2bf(o5) << 16);
        u.w = (uint_t)f2bf(o6) | ((uint_t)f2bf(o7) << 16);
        *(uint4*)(zb + (size_t)wid * 64 + lane * 8) = u;
    }
}

// ---------- MFMA fused 2-layer MLP ----------
#define HSTRIDE 136
__global__ __launch_bounds__(256) void mlp_kernel(const ushort_t* __restrict__ zb,
                                                  const ushort_t* __restrict__ w1f,
                                                  const float* __restrict__ b1,
                                                  const ushort_t* __restrict__ w2f,
                                                  const float* __restrict__ b2,
                                                  ushort_t* __restrict__ hbout, int n) {
    __shared__ ushort_t hid[64 * HSTRIDE];
    int tid = threadIdx.x;
    int w = tid >> 6, lane = tid & 63, m = lane & 15, q = lane >> 4;
    for (int i = tid; i < 64 * 32; i += 256) {
        int r = i >> 5, c = HID2 + (i & 31);
        hid[r * HSTRIDE + c] = 0;
    }
    __syncthreads();

    int nb = blockIdx.x * 64 + w * 16;
    f32x4 acc1[7];
#pragma unroll
    for (int ct = 0; ct < 7; ct++) {
        int col = ct * 16 + m;
        float bv = (col < HID2) ? b1[col] : 0.f;
        acc1[ct] = (f32x4){bv, bv, bv, bv};
    }
    int anode = min(nb + m, n - 1);
#pragma unroll
    for (int ks = 0; ks < 2; ks++) {
        bf16x8 a = *(const bf16x8*)(zb + (size_t)anode * 64 + ks * 32 + q * 8);
#pragma unroll
        for (int ct = 0; ct < 7; ct++) {
            bf16x8 b = *(const bf16x8*)(w1f + ((size_t)(ct * 2 + ks) * 64 + lane) * 8);
            acc1[ct] = __builtin_amdgcn_mfma_f32_16x16x32_bf16(a, b, acc1[ct], 0, 0, 0);
        }
    }
#pragma unroll
    for (int ct = 0; ct < 7; ct++) {
#pragma unroll
        for (int r = 0; r < 4; r++) {
            float v = fmaxf(acc1[ct][r], 0.f);
            int row = w * 16 + q * 4 + r;
            hid[row * HSTRIDE + ct * 16 + m] = f2bf(v);
        }
    }
    f32x4 acc2[4];
#pragma unroll
    for (int ct = 0; ct < 4; ct++) {
        int col = ct * 16 + m;
        float bv = (col < HID) ? b2[col] : 0.f;
        acc2[ct] = (f32x4){bv, bv, bv, bv};
    }
#pragma unroll
    for (int ks = 0; ks < 4; ks++) {
        bf16x8 a = *(const bf16x8*)&hid[(w * 16 + m) * HSTRIDE + ks * 32 + q * 8];
#pragma unroll
        for (int ct = 0; ct < 4; ct++) {
            bf16x8 b = *(const bf16x8*)(w2f + ((size_t)(ct * 4 + ks) * 64 + lane) * 8);
            acc2[ct] = __builtin_amdgcn_mfma_f32_16x16x32_bf16(a, b, acc2[ct], 0, 0, 0);
        }
    }
#pragma unroll
    for (int ct = 0; ct < 4; ct++) {
#pragma unroll
        for (int r = 0; r < 4; r++) {
            int node = nb + q * 4 + r;
            if (node < n) {
                float v = fmaxf(acc2[ct][r], 0.f);
                hbout[(size_t)node * 64 + ct * 16 + m] = f2bf(v);
            }
        }
    }
}

// ---------- MFMA final ----------
__global__ __launch_bounds__(256) void final_kernel(const ushort_t* __restrict__ xb,
                                                    const ushort_t* __restrict__ h1b,
                                                    const ushort_t* __restrict__ h2b,
                                                    const ushort_t* __restrict__ h3b,
                                                    const ushort_t* __restrict__ linf,
                                                    const float* __restrict__ lin_b,
                                                    float* __restrict__ out, int ntiles) {
    int tid = threadIdx.x;
    int w = tid >> 6, lane = tid & 63, m = lane & 15, q = lane >> 4;
    int tile = blockIdx.x * 4 + w;
    if (tile >= ntiles) return;
    int nb = tile * 16;
    const ushort_t* segs[4] = {xb, h1b, h2b, h3b};
    f32x4 acc[4];
#pragma unroll
    for (int ct = 0; ct < 4; ct++) {
        int col = ct * 16 + m;
        float bv = (col < HID) ? lin_b[col] : 0.f;
        acc[ct] = (f32x4){bv, bv, bv, bv};
    }
#pragma unroll
    for (int ks = 0; ks < 8; ks++) {
        const ushort_t* p = segs[ks >> 1];
        bf16x8 a = *(const bf16x8*)(p + (size_t)(nb + m) * 64 + (ks & 1) * 32 + q * 8);
#pragma unroll
        for (int ct = 0; ct < 4; ct++) {
            bf16x8 b = *(const bf16x8*)(linf + ((size_t)(ct * 8 + ks) * 64 + lane) * 8);
            acc[ct] = __builtin_amdgcn_mfma_f32_16x16x32_bf16(a, b, acc[ct], 0, 0, 0);
        }
    }
#pragma unroll
    for (int ct = 0; ct < 4; ct++) {
        int col = ct * 16 + m;
        if (col < HID) {
#pragma unroll
            for (int r = 0; r < 4; r++)
                out[(size_t)(nb + q * 4 + r) * HID + col] = acc[ct][r];
        }
    }
}

extern "C" void kernel_launch(void* const* d_in, const int* in_sizes, int n_in,
                              void* d_out, int out_size, void* d_ws, size_t ws_size,
                              hipStream_t stream) {
    const float* x     = (const float*)d_in[0];
    const int*   ei    = (const int*)d_in[1];
    const float* w1    = (const float*)d_in[2];
    const float* b1    = (const float*)d_in[3];
    const float* w2    = (const float*)d_in[4];
    const float* b2    = (const float*)d_in[5];
    const float* eps   = (const float*)d_in[6];
    const float* lin_w = (const float*)d_in[7];
    const float* lin_b = (const float*)d_in[8];
    float* out = (float*)d_out;

    const int N = in_sizes[0] / HID;       // 100000
    const int E = in_sizes[1] / 2;         // 3200000
    const int* src = ei;
    const int* dst = ei + E;

    const int NBIN = (N + 255) / 256;      // 391

    // ---- workspace layout (16B-aligned blocks); bf16 tables have extra zero row N ----
    char* p = (char*)d_ws;
    const size_t ROWS = (size_t)(N + 1) * 64 * 2;
    ushort_t* xb  = (ushort_t*)p;  p += ROWS;
    ushort_t* zb  = (ushort_t*)p;  p += ROWS;
    ushort_t* h1b = (ushort_t*)p;  p += ROWS;
    ushort_t* h2b = (ushort_t*)p;  p += ROWS;
    ushort_t* h3b = (ushort_t*)p;  p += ROWS;
    ushort_t* w1f = (ushort_t*)p;  p += 3 * 14 * 512 * 2;
    ushort_t* w2f = (ushort_t*)p;  p += 3 * 16 * 512 * 2;
    ushort_t* linf= (ushort_t*)p;  p += 32 * 512 * 2;
    int* ghist    = (int*)p;       p += 528 * 4;
    int* binstart = (int*)p;       p += 528 * 4;
    int* gcur     = (int*)p;       p += 528 * 4;
    int* nrs      = (int*)p;       p += (size_t)(N + 4) * 4;
    int* ndeg     = (int*)p;       p += (size_t)(N + 4) * 4;
    uint_t* packed = (uint_t*)p;   p += (size_t)E * 4;
    int* srcsorted = (int*)p;      // E + NBIN*4096 + 64 entries (prefetch slack)

    ushort_t* hbs[4] = {xb, h1b, h2b, h3b};

    const int BLK = 256;
    const int NP1 = (E + P1_CHUNK - 1) / P1_CHUNK;   // 391
    const int NXBLK = (N * 16 + BLK - 1) / BLK;      // 6250
    dim3 blk(BLK);
    dim3 grid_agg(((size_t)N * 64 + BLK - 1) / BLK);

    // ---- fused setup (also zeroes ghist) then CSR build ----
    setup_kernel<<<NXBLK + 1 + 31, blk, 0, stream>>>(x, w1, w2, lin_w,
                                                     xb, h1b, h2b, h3b,
                                                     w1f, w2f, linf, ghist, N, NXBLK);
    bhist_kernel<<<NP1, blk, 0, stream>>>(dst, ghist, E);
    bscan_kernel<<<1, blk, 0, stream>>>(ghist, binstart, gcur, NBIN, E);
    pass1_kernel<<<NP1, blk, 0, stream>>>(src, dst, gcur, packed, E);
    pass2_kernel<<<NBIN, blk, 0, stream>>>(packed, binstart, srcsorted, nrs, ndeg, N);

    // ---- layers ----
    const int NBUCK = (N + 63) / 64;
    for (int l = 0; l < 3; l++) {
        agg_kernel<<<grid_agg, blk, 0, stream>>>(hbs[l], nrs, ndeg, srcsorted, eps + l, zb, N);
        mlp_kernel<<<NBUCK, blk, 0, stream>>>(zb,
                                              w1f + (size_t)l * 14 * 512,
                                              b1 + (size_t)l * HID2,
                                              w2f + (size_t)l * 16 * 512,
                                              b2 + (size_t)l * HID,
                                              hbs[l + 1], N);
    }
    final_kernel<<<(6250 + 3) / 4 + 1, blk, 0, stream>>>(xb, h1b, h2b, h3b, linf, lin_b,
                                                         out, (N + 15) / 16);
}